// Round 11
// baseline (662.575 us; speedup 1.0000x reference)
//
#include <hip/hip_runtime.h>
#include <math.h>

#define HD   256
#define FIN  32
#define NP   8192
#define PGH  4096
#define NLVL 15
#define TN   16    // nodes per block tile

__device__ __forceinline__ float lrelu(float x) { return x > 0.f ? x : 0.1f * x; }

// ---------------- pi kernel: prev_h = mlp(delay), + sdot epilogue ----------------
__global__ __launch_bounds__(256) void pi_kernel(
    const float* __restrict__ delay,
    const float* __restrict__ w1, const float* __restrict__ b1,
    const float* __restrict__ w2, const float* __restrict__ b2,
    const float* __restrict__ av,
    float* __restrict__ outh, float* __restrict__ sdot)
{
    __shared__ float g1[TN][132];
    const int tid = threadIdx.x;
    const int node0 = blockIdx.x * TN;

    for (int t = tid; t < TN * 128; t += 256) {
        int i = t >> 7, jj = t & 127;
        g1[i][jj] = lrelu(delay[node0 + i] * w1[jj] + b1[jj]);
    }
    __syncthreads();

    const int j = (tid & 63) * 4;
    const int rg = (tid >> 6) * 4;
    float acc[4][4];
    float4 bv = *(const float4*)&b2[j];
#pragma unroll
    for (int ri = 0; ri < 4; ri++) { acc[ri][0] = bv.x; acc[ri][1] = bv.y; acc[ri][2] = bv.z; acc[ri][3] = bv.w; }

#pragma unroll 2
    for (int k = 0; k < 128; k += 4) {
        float4 x0 = *(const float4*)&g1[rg + 0][k];
        float4 x1 = *(const float4*)&g1[rg + 1][k];
        float4 x2v = *(const float4*)&g1[rg + 2][k];
        float4 x3 = *(const float4*)&g1[rg + 3][k];
        const float* wp = w2 + (size_t)k * 256 + j;
#define PIK(comp, off) { float4 wv = *(const float4*)(wp + (off) * 256); \
    acc[0][0] += x0.comp * wv.x; acc[0][1] += x0.comp * wv.y; acc[0][2] += x0.comp * wv.z; acc[0][3] += x0.comp * wv.w; \
    acc[1][0] += x1.comp * wv.x; acc[1][1] += x1.comp * wv.y; acc[1][2] += x1.comp * wv.z; acc[1][3] += x1.comp * wv.w; \
    acc[2][0] += x2v.comp * wv.x; acc[2][1] += x2v.comp * wv.y; acc[2][2] += x2v.comp * wv.z; acc[2][3] += x2v.comp * wv.w; \
    acc[3][0] += x3.comp * wv.x; acc[3][1] += x3.comp * wv.y; acc[3][2] += x3.comp * wv.z; acc[3][3] += x3.comp * wv.w; }
        PIK(x, 0) PIK(y, 1) PIK(z, 2) PIK(w, 3)
#undef PIK
    }
    float4 avj = *(const float4*)&av[64 + j];
#pragma unroll
    for (int ri = 0; ri < 4; ri++) {
        *(float4*)&outh[(node0 + rg + ri) * HD + j] =
            make_float4(acc[ri][0], acc[ri][1], acc[ri][2], acc[ri][3]);
        float p = acc[ri][0] * avj.x + acc[ri][1] * avj.y + acc[ri][2] * avj.z + acc[ri][3] * avj.w;
#pragma unroll
        for (int off = 1; off < 64; off <<= 1) p += __shfl_xor(p, off);
        if ((tid & 63) == 0) sdot[node0 + rg + ri] = p;
    }
}

// ---------------- per-level kernel: 512 threads; blocks 0..255 gate, 256..511 mod ----------------
__global__ __launch_bounds__(512, 4) void level_kernel(
    const float* __restrict__ prevh, float* __restrict__ nexth,
    const float* __restrict__ sdot_prev, float* __restrict__ sdot_next,
    const float* __restrict__ feat, const float* __restrict__ bitpos,
    const int* __restrict__ srcidx,
    const float* __restrict__ g_w1, const float* __restrict__ g_b1,
    const float* __restrict__ g_w2, const float* __restrict__ g_b2,
    const float* __restrict__ m_w1, const float* __restrict__ m_b1,
    const float* __restrict__ m_w2, const float* __restrict__ m_b2,
    const float* __restrict__ t_w1, const float* __restrict__ t_b1,
    const float* __restrict__ t_w2, const float* __restrict__ t_b2,
    const float* __restrict__ p_w1, const float* __restrict__ p_b1,
    const float* __restrict__ p_w2, const float* __restrict__ p_b2,
    const float* __restrict__ av,
    int level, int apply_relu)
{
    __shared__ float x_lds[TN][292];
    __shared__ float h1_lds[TN][132];
    __shared__ float wbuf[2][4096];     // 32 KB double-buffered weight staging
    __shared__ int   src_lds[TN * 8];
    __shared__ float bp_lds[TN * 8];
    __shared__ float dstf_lds[TN][32];
    __shared__ float ztt_lds[TN][32];
    __shared__ float alpha_lds[TN * 8];
    __shared__ float xbp_lds[TN];
    __shared__ float av_lds[64];
    __shared__ float tw2av_lds[32];
    __shared__ float pw2av_lds[32];
    __shared__ float bias_av[2];
    __shared__ float red_lds[TN][2];

    const int tid = threadIdx.x;
    const bool is_gate = (blockIdx.x < 256);
    const int node0 = is_gate ? (blockIdx.x * TN) : (PGH + ((int)blockIdx.x - 256) * TN);

    const float* w1 = is_gate ? g_w1 : m_w1;
    const float* b1 = is_gate ? g_b1 : m_b1;
    const float* w2 = is_gate ? g_w2 : m_w2;
    const float* b2 = is_gate ? g_b2 : m_b2;
    const float4* wg1 = (const float4*)w1;

    // issue GEMM1 chunk-0 weight loads now; they land during the gather phase
    float4 ta = wg1[tid], tb = wg1[tid + 512];

    if (tid < TN * 8) src_lds[tid] = srcidx[(level * NP + node0) * 8 + tid];

    if (is_gate) {
        {
            int i = tid >> 5, k = tid & 31;                    // 512 = TN*32 exactly
            x_lds[i][256 + k] = feat[((level + 1) * NP + node0 + i) * FIN + k];
        }
        __syncthreads();
        // gather + per-channel softmax: thread = (half, channel), 4-node chunks
        {
            const int c = tid & 255, sh = (tid >> 8) * 8;
            for (int s0 = 0; s0 < 8; s0 += 4) {
                const int* spA = &src_lds[(sh + s0 + 0) * 8];
                const int* spB = &src_lds[(sh + s0 + 1) * 8];
                const int* spC = &src_lds[(sh + s0 + 2) * 8];
                const int* spD = &src_lds[(sh + s0 + 3) * 8];
                float ma[8], mb[8], mc[8], md[8];
#pragma unroll
                for (int f = 0; f < 8; f++) ma[f] = prevh[spA[f] * HD + c];
#pragma unroll
                for (int f = 0; f < 8; f++) mb[f] = prevh[spB[f] * HD + c];
#pragma unroll
                for (int f = 0; f < 8; f++) mc[f] = prevh[spC[f] * HD + c];
#pragma unroll
                for (int f = 0; f < 8; f++) md[f] = prevh[spD[f] * HD + c];
                float mxa = -1e30f, mxb = -1e30f, mxc = -1e30f, mxd = -1e30f;
#pragma unroll
                for (int f = 0; f < 8; f++) {
                    mxa = fmaxf(mxa, ma[f]); mxb = fmaxf(mxb, mb[f]);
                    mxc = fmaxf(mxc, mc[f]); mxd = fmaxf(mxd, md[f]);
                }
                float sa = 0.f, wsa = 0.f, sb = 0.f, wsb = 0.f;
                float sc = 0.f, wsc = 0.f, sd = 0.f, wsd = 0.f;
#pragma unroll
                for (int f = 0; f < 8; f++) {
                    float ea = __expf(ma[f] - mxa); sa += ea; wsa += ma[f] * ea;
                    float eb = __expf(mb[f] - mxb); sb += eb; wsb += mb[f] * eb;
                    float ec = __expf(mc[f] - mxc); sc += ec; wsc += mc[f] * ec;
                    float ed = __expf(md[f] - mxd); sd += ed; wsd += md[f] * ed;
                }
                x_lds[sh + s0 + 0][c] = wsa / sa;
                x_lds[sh + s0 + 1][c] = wsb / sb;
                x_lds[sh + s0 + 2][c] = wsc / sc;
                x_lds[sh + s0 + 3][c] = wsd / sd;
            }
        }
        __syncthreads();
    } else {
        if (tid < TN * 8) bp_lds[tid] = bitpos[(level * NP + node0) * 8 + tid];
        {
            int i = tid >> 5, k = tid & 31;
            dstf_lds[i][k] = feat[((level + 1) * NP + node0 + i) * FIN + k];
        }
        if (tid < 64) av_lds[tid] = av[tid];
        __syncthreads();

        // ztt = lrelu(dstf @ t_w1 + t_b1): one output per thread (512 = 16*32)
        {
            int i = tid >> 5, jj = tid & 31;
            float a = t_b1[jj];
#pragma unroll 8
            for (int k = 0; k < 32; k++) a += dstf_lds[i][k] * t_w1[k * 32 + jj];
            ztt_lds[i][jj] = lrelu(a);
        }
        // fold attn_vec through second MLP layers (exact linear reassociation)
        if (tid < 32) {
            float s = 0.f;
#pragma unroll 8
            for (int jj = 0; jj < 32; jj++) s += t_w2[tid * 32 + jj] * av_lds[jj];
            tw2av_lds[tid] = s;
        } else if (tid < 64) {
            int k = tid - 32;
            float s = 0.f;
#pragma unroll 8
            for (int jj = 0; jj < 32; jj++) s += p_w2[k * 32 + jj] * av_lds[32 + jj];
            pw2av_lds[k] = s;
        } else if (tid == 64) {
            float s = 0.f;
#pragma unroll 8
            for (int jj = 0; jj < 32; jj++) s += t_b2[jj] * av_lds[jj];
            bias_av[0] = s;
        } else if (tid == 65) {
            float s = 0.f;
#pragma unroll 8
            for (int jj = 0; jj < 32; jj++) s += p_b2[jj] * av_lds[32 + jj];
            bias_av[1] = s;
        }
        __syncthreads();

        // logits + softmax over fanin: first 256 threads, tid = i*16 + f*2 + jg
        if (tid < 256) {
            const int jg = tid & 1, f = (tid >> 1) & 7, i = tid >> 4;
            const float sv = sdot_prev[src_lds[i * 8 + f]];   // hoisted row dot
            const float bpv = bp_lds[i * 8 + f];
            float part = 0.f;
            const int k0 = jg * 16;
#pragma unroll
            for (int k = k0; k < k0 + 16; k++) {
                float h1pk = lrelu(bpv * p_w1[k] + p_b1[k]);
                part += h1pk * pw2av_lds[k];
                part += ztt_lds[i][k] * tw2av_lds[k];
            }
            part += __shfl_xor(part, 1);
            float logit = part + bias_av[0] + bias_av[1] + sv;
            float mx = logit;
            mx = fmaxf(mx, __shfl_xor(mx, 2));
            mx = fmaxf(mx, __shfl_xor(mx, 4));
            mx = fmaxf(mx, __shfl_xor(mx, 8));
            float e = __expf(logit - mx);
            float ssum = e;
            ssum += __shfl_xor(ssum, 2);
            ssum += __shfl_xor(ssum, 4);
            ssum += __shfl_xor(ssum, 8);
            float alpha = e / ssum;
            if (jg == 0) alpha_lds[i * 8 + f] = alpha;
            float ab = alpha * bpv;
            ab += __shfl_xor(ab, 2);
            ab += __shfl_xor(ab, 4);
            ab += __shfl_xor(ab, 8);
            if ((tid & 15) == 0) xbp_lds[i] = ab;
        }
        __syncthreads();

        // neigh_m: thread = (half, channel), 4-node chunks; assemble x
        {
            const int c = tid & 255, sh = (tid >> 8) * 8;
            for (int s0 = 0; s0 < 8; s0 += 4) {
                const int* spA = &src_lds[(sh + s0 + 0) * 8];
                const int* spB = &src_lds[(sh + s0 + 1) * 8];
                const int* spC = &src_lds[(sh + s0 + 2) * 8];
                const int* spD = &src_lds[(sh + s0 + 3) * 8];
                float ma[8], mb[8], mc[8], md[8];
#pragma unroll
                for (int f = 0; f < 8; f++) ma[f] = prevh[spA[f] * HD + c];
#pragma unroll
                for (int f = 0; f < 8; f++) mb[f] = prevh[spB[f] * HD + c];
#pragma unroll
                for (int f = 0; f < 8; f++) mc[f] = prevh[spC[f] * HD + c];
#pragma unroll
                for (int f = 0; f < 8; f++) md[f] = prevh[spD[f] * HD + c];
                const float* apA = &alpha_lds[(sh + s0 + 0) * 8];
                const float* apB = &alpha_lds[(sh + s0 + 1) * 8];
                const float* apC = &alpha_lds[(sh + s0 + 2) * 8];
                const float* apD = &alpha_lds[(sh + s0 + 3) * 8];
                float aa = 0.f, ab2 = 0.f, ac = 0.f, ad = 0.f;
#pragma unroll
                for (int f = 0; f < 8; f++) {
                    aa  += apA[f] * ma[f]; ab2 += apB[f] * mb[f];
                    ac  += apC[f] * mc[f]; ad  += apD[f] * md[f];
                }
                x_lds[sh + s0 + 0][c] = aa;
                x_lds[sh + s0 + 1][c] = ab2;
                x_lds[sh + s0 + 2][c] = ac;
                x_lds[sh + s0 + 3][c] = ad;
            }
        }
        if (tid < TN) x_lds[tid][256] = xbp_lds[tid];
        {
            int i = tid >> 5, k = tid & 31;
            x_lds[i][257 + k] = dstf_lds[i][k];
        }
        __syncthreads();
    }

    // ---------- GEMM1: (16 x K1)@(K1 x 128); acc[4][1], 4 row-groups; dbuf staged ----------
    {
        const int col = tid & 127;
        const int rg = (tid >> 7) * 4;
        float acc0 = b1[col], acc1 = acc0, acc2 = acc0, acc3 = acc0;

        for (int c = 0; c < 9; ++c) {            // 9 chunks of 32 k (32x128 = 1024 f4)
            float* buf = wbuf[c & 1];
            float4* w4 = (float4*)buf;
            w4[tid] = ta; w4[tid + 512] = tb;
            if (c < 8) {
                const float4* gn = wg1 + (size_t)(c + 1) * 1024;
                ta = gn[tid]; tb = gn[tid + 512];
            }
            __syncthreads();
            const int kc = c * 32;
#pragma unroll 2
            for (int k = 0; k < 32; k += 4) {
                float4 x0 = *(const float4*)&x_lds[rg + 0][kc + k];
                float4 x1 = *(const float4*)&x_lds[rg + 1][kc + k];
                float4 x2v = *(const float4*)&x_lds[rg + 2][kc + k];
                float4 x3 = *(const float4*)&x_lds[rg + 3][kc + k];
                const float* wp = buf + k * 128 + col;
#define G1K(comp, off) { float wv = wp[(off) * 128]; \
    acc0 += x0.comp * wv; acc1 += x1.comp * wv; acc2 += x2v.comp * wv; acc3 += x3.comp * wv; }
                G1K(x, 0) G1K(y, 1) G1K(z, 2) G1K(w, 3)
#undef G1K
            }
        }
        if (!is_gate) {
            float wt = w1[288 * 128 + col];
            acc0 += x_lds[rg + 0][288] * wt;
            acc1 += x_lds[rg + 1][288] * wt;
            acc2 += x_lds[rg + 2][288] * wt;
            acc3 += x_lds[rg + 3][288] * wt;
        }
        // issue GEMM2 chunk-0 loads; they land during the epilogue + barrier
        {
            const float4* wg2 = (const float4*)w2;
            ta = wg2[tid]; tb = wg2[tid + 512];
        }
        h1_lds[rg + 0][col] = lrelu(acc0);
        h1_lds[rg + 1][col] = lrelu(acc1);
        h1_lds[rg + 2][col] = lrelu(acc2);
        h1_lds[rg + 3][col] = lrelu(acc3);
    }
    __syncthreads();

    // ---------- GEMM2: (16 x 128)@(128 x 256) + relu + sdot; acc[4][2]; dbuf staged ----------
    {
        const int j = (tid & 127) * 2;
        const int rg = (tid >> 7) * 4;
        float acc[4][2];
        float2 bv = *(const float2*)&b2[j];
#pragma unroll
        for (int ri = 0; ri < 4; ri++) { acc[ri][0] = bv.x; acc[ri][1] = bv.y; }

        const float4* wg2 = (const float4*)w2;
        for (int c = 0; c < 8; ++c) {            // 8 chunks of 16 k (16x256 = 1024 f4)
            float* buf = wbuf[c & 1];
            float4* w4 = (float4*)buf;
            w4[tid] = ta; w4[tid + 512] = tb;
            if (c < 7) {
                const float4* gn = wg2 + (size_t)(c + 1) * 1024;
                ta = gn[tid]; tb = gn[tid + 512];
            }
            __syncthreads();
            const int kc = c * 16;
#pragma unroll 2
            for (int k = 0; k < 16; k += 4) {
                float4 x0 = *(const float4*)&h1_lds[rg + 0][kc + k];
                float4 x1 = *(const float4*)&h1_lds[rg + 1][kc + k];
                float4 x2v = *(const float4*)&h1_lds[rg + 2][kc + k];
                float4 x3 = *(const float4*)&h1_lds[rg + 3][kc + k];
                const float* wp = buf + k * 256 + j;
#define G2K(comp, off) { float2 wv = *(const float2*)(wp + (off) * 256); \
    acc[0][0] += x0.comp * wv.x; acc[0][1] += x0.comp * wv.y; \
    acc[1][0] += x1.comp * wv.x; acc[1][1] += x1.comp * wv.y; \
    acc[2][0] += x2v.comp * wv.x; acc[2][1] += x2v.comp * wv.y; \
    acc[3][0] += x3.comp * wv.x; acc[3][1] += x3.comp * wv.y; }
                G2K(x, 0) G2K(y, 1) G2K(z, 2) G2K(w, 3)
#undef G2K
            }
        }
        float av0 = av[64 + j], av1 = av[64 + j + 1];
        const int wh = (tid >> 6) & 1;           // wave-half within 128-thread group
#pragma unroll
        for (int ri = 0; ri < 4; ri++) {
            if (apply_relu) { acc[ri][0] = fmaxf(acc[ri][0], 0.f); acc[ri][1] = fmaxf(acc[ri][1], 0.f); }
            *(float2*)&nexth[(node0 + rg + ri) * HD + j] = make_float2(acc[ri][0], acc[ri][1]);
            float p = acc[ri][0] * av0 + acc[ri][1] * av1;
#pragma unroll
            for (int off = 1; off < 64; off <<= 1) p += __shfl_xor(p, off);
            if ((tid & 63) == 0) red_lds[rg + ri][wh] = p;
        }
        __syncthreads();
        if (tid < TN) sdot_next[node0 + tid] = red_lds[tid][0] + red_lds[tid][1];
    }
}

// ---------------- final kernel: 512 threads; glob mlp + concat + out mlp (fused) ----------------
__global__ __launch_bounds__(512, 4) void final_kernel(
    const float* __restrict__ prevh, const float* __restrict__ pofeat,
    const float* __restrict__ gl_w1, const float* __restrict__ gl_b1,
    const float* __restrict__ gl_w2, const float* __restrict__ gl_b2,
    const float* __restrict__ o_w1, const float* __restrict__ o_b1,
    const float* __restrict__ o_w2, const float* __restrict__ o_b2,
    float* __restrict__ out)
{
    __shared__ float x2[TN][516];
    __shared__ float g1[TN][132];
    __shared__ float wbuf[2][4096];
    __shared__ float ow2_lds[256];
    __shared__ float red_lds[TN][2];

    const int tid = threadIdx.x;
    const int node0 = blockIdx.x * TN;
    const int j = (tid & 127) * 2;
    const int rg = (tid >> 7) * 4;

    const float4* wgl = (const float4*)gl_w2;
    float4 ta = wgl[tid], tb = wgl[tid + 512];

    for (int q = tid; q < TN * 64; q += 512) {
        int i = q >> 6, c4 = (q & 63) * 4;
        *(float4*)&x2[i][c4] = *(const float4*)&prevh[(node0 + i) * HD + c4];
    }
    for (int t = tid; t < TN * 128; t += 512) {
        int i = t >> 7, jj = t & 127;
        g1[i][jj] = lrelu(pofeat[node0 + i] * gl_w1[jj] + gl_b1[jj]);
    }
    if (tid < 256) ow2_lds[tid] = o_w2[tid];
    __syncthreads();

    // glob layer 2: (16 x 128)@(128 x 256) -> x2 cols 256..511; acc[4][2]; dbuf staged
    {
        float acc[4][2];
        float2 bv = *(const float2*)&gl_b2[j];
#pragma unroll
        for (int ri = 0; ri < 4; ri++) { acc[ri][0] = bv.x; acc[ri][1] = bv.y; }
        for (int c = 0; c < 8; ++c) {
            float* buf = wbuf[c & 1];
            float4* w4 = (float4*)buf;
            w4[tid] = ta; w4[tid + 512] = tb;
            if (c < 7) {
                const float4* gn = wgl + (size_t)(c + 1) * 1024;
                ta = gn[tid]; tb = gn[tid + 512];
            } else {
                const float4* gn = (const float4*)o_w1;   // prefetch out1 chunk 0
                ta = gn[tid]; tb = gn[tid + 512];
            }
            __syncthreads();
            const int kc = c * 16;
#pragma unroll 2
            for (int k = 0; k < 16; k += 4) {
                float4 x0 = *(const float4*)&g1[rg + 0][kc + k];
                float4 x1 = *(const float4*)&g1[rg + 1][kc + k];
                float4 x2v = *(const float4*)&g1[rg + 2][kc + k];
                float4 x3 = *(const float4*)&g1[rg + 3][kc + k];
                const float* wp = buf + k * 256 + j;
#define GLK(comp, off) { float2 wv = *(const float2*)(wp + (off) * 256); \
    acc[0][0] += x0.comp * wv.x; acc[0][1] += x0.comp * wv.y; \
    acc[1][0] += x1.comp * wv.x; acc[1][1] += x1.comp * wv.y; \
    acc[2][0] += x2v.comp * wv.x; acc[2][1] += x2v.comp * wv.y; \
    acc[3][0] += x3.comp * wv.x; acc[3][1] += x3.comp * wv.y; }
                GLK(x, 0) GLK(y, 1) GLK(z, 2) GLK(w, 3)
#undef GLK
            }
        }
#pragma unroll
        for (int ri = 0; ri < 4; ri++)
            *(float2*)&x2[rg + ri][256 + j] = make_float2(acc[ri][0], acc[ri][1]);
    }
    __syncthreads();

    // out layer 1 (dbuf staged, 32 chunks); acc[4][2]; fused with out layer 2
    {
        float acc[4][2];
        float2 bv = *(const float2*)&o_b1[j];
#pragma unroll
        for (int ri = 0; ri < 4; ri++) { acc[ri][0] = bv.x; acc[ri][1] = bv.y; }
        const float4* wo = (const float4*)o_w1;
        for (int c = 0; c < 32; ++c) {
            float* buf = wbuf[c & 1];
            float4* w4 = (float4*)buf;
            w4[tid] = ta; w4[tid + 512] = tb;
            if (c < 31) {
                const float4* gn = wo + (size_t)(c + 1) * 1024;
                ta = gn[tid]; tb = gn[tid + 512];
            }
            __syncthreads();
            const int kc = c * 16;
#pragma unroll 2
            for (int k = 0; k < 16; k += 4) {
                float4 x0 = *(const float4*)&x2[rg + 0][kc + k];
                float4 x1 = *(const float4*)&x2[rg + 1][kc + k];
                float4 x2v = *(const float4*)&x2[rg + 2][kc + k];
                float4 x3 = *(const float4*)&x2[rg + 3][kc + k];
                const float* wp = buf + k * 256 + j;
#define O1K(comp, off) { float2 wv = *(const float2*)(wp + (off) * 256); \
    acc[0][0] += x0.comp * wv.x; acc[0][1] += x0.comp * wv.y; \
    acc[1][0] += x1.comp * wv.x; acc[1][1] += x1.comp * wv.y; \
    acc[2][0] += x2v.comp * wv.x; acc[2][1] += x2v.comp * wv.y; \
    acc[3][0] += x3.comp * wv.x; acc[3][1] += x3.comp * wv.y; }
                O1K(x, 0) O1K(y, 1) O1K(z, 2) O1K(w, 3)
#undef O1K
            }
        }
        // out layer 2: per-row dot over 256 cols, split across the group's 2 waves
        float w0 = ow2_lds[j], w1v = ow2_lds[j + 1];
        const int wh = (tid >> 6) & 1;
#pragma unroll
        for (int ri = 0; ri < 4; ri++) {
            float p = lrelu(acc[ri][0]) * w0 + lrelu(acc[ri][1]) * w1v;
#pragma unroll
            for (int off = 1; off < 64; off <<= 1) p += __shfl_xor(p, off);
            if ((tid & 63) == 0) red_lds[rg + ri][wh] = p;
        }
        __syncthreads();
        if (tid < TN) out[node0 + tid] = red_lds[tid][0] + red_lds[tid][1] + o_b2[0];
    }
}

extern "C" void kernel_launch(void* const* d_in, const int* in_sizes, int n_in,
                              void* d_out, int out_size, void* d_ws, size_t ws_size,
                              hipStream_t stream)
{
    const float* delay    = (const float*)d_in[0];
    const float* feat     = (const float*)d_in[1];
    const float* bitpos   = (const float*)d_in[2];
    const float* pofeat   = (const float*)d_in[3];
    const int*   srcidx   = (const int*)  d_in[4];
    const float* pi_w1    = (const float*)d_in[5];
    const float* pi_b1    = (const float*)d_in[6];
    const float* pi_w2    = (const float*)d_in[7];
    const float* pi_b2    = (const float*)d_in[8];
    const float* gate_w1  = (const float*)d_in[9];
    const float* gate_b1  = (const float*)d_in[10];
    const float* gate_w2  = (const float*)d_in[11];
    const float* gate_b2  = (const float*)d_in[12];
    const float* mod_w1   = (const float*)d_in[13];
    const float* mod_b1   = (const float*)d_in[14];
    const float* mod_w2   = (const float*)d_in[15];
    const float* mod_b2   = (const float*)d_in[16];
    const float* type_w1  = (const float*)d_in[17];
    const float* type_b1  = (const float*)d_in[18];
    const float* type_w2  = (const float*)d_in[19];
    const float* type_b2  = (const float*)d_in[20];
    const float* pos_w1   = (const float*)d_in[21];
    const float* pos_b1   = (const float*)d_in[22];
    const float* pos_w2   = (const float*)d_in[23];
    const float* pos_b2   = (const float*)d_in[24];
    const float* attn_vec = (const float*)d_in[25];
    const float* glob_w1  = (const float*)d_in[26];
    const float* glob_b1  = (const float*)d_in[27];
    const float* glob_w2  = (const float*)d_in[28];
    const float* glob_b2  = (const float*)d_in[29];
    const float* out_w1   = (const float*)d_in[30];
    const float* out_b1   = (const float*)d_in[31];
    const float* out_w2   = (const float*)d_in[32];
    const float* out_b2   = (const float*)d_in[33];

    float* buf0 = (float*)d_ws;
    float* buf1 = buf0 + (size_t)NP * HD;
    float* sd0  = buf1 + (size_t)NP * HD;
    float* sd1  = sd0 + NP;

    pi_kernel<<<NP / TN, 256, 0, stream>>>(delay, pi_w1, pi_b1, pi_w2, pi_b2,
                                           attn_vec, buf0, sd0);

    for (int l = 0; l < NLVL; l++) {
        float* pv = (l & 1) ? buf1 : buf0;
        float* nx = (l & 1) ? buf0 : buf1;
        float* sp = (l & 1) ? sd1 : sd0;
        float* sn = (l & 1) ? sd0 : sd1;
        level_kernel<<<NP / TN, 512, 0, stream>>>(
            pv, nx, sp, sn, feat, bitpos, srcidx,
            gate_w1, gate_b1, gate_w2, gate_b2,
            mod_w1, mod_b1, mod_w2, mod_b2,
            type_w1, type_b1, type_w2, type_b2,
            pos_w1, pos_b1, pos_w2, pos_b2,
            attn_vec, l, (l != NLVL - 1) ? 1 : 0);
    }

    final_kernel<<<NP / TN, 512, 0, stream>>>(
        buf1, pofeat,
        glob_w1, glob_b1, glob_w2, glob_b2,
        out_w1, out_b1, out_w2, out_b2,
        (float*)d_out);
}

// Round 12
// 568.275 us; speedup vs baseline: 1.1659x; 1.1659x over previous
//
#include <hip/hip_runtime.h>
#include <math.h>

#define HD   256
#define FIN  32
#define NP   8192
#define PGH  4096
#define NLVL 15
#define TN   16    // nodes per block tile

__device__ __forceinline__ float lrelu(float x) { return x > 0.f ? x : 0.1f * x; }

// ---------------- pi kernel: prev_h = mlp(delay), + sdot epilogue ----------------
__global__ __launch_bounds__(256) void pi_kernel(
    const float* __restrict__ delay,
    const float* __restrict__ w1, const float* __restrict__ b1,
    const float* __restrict__ w2, const float* __restrict__ b2,
    const float* __restrict__ av,
    float* __restrict__ outh, float* __restrict__ sdot)
{
    __shared__ float g1[TN][132];
    const int tid = threadIdx.x;
    const int node0 = blockIdx.x * TN;

    for (int t = tid; t < TN * 128; t += 256) {
        int i = t >> 7, jj = t & 127;
        g1[i][jj] = lrelu(delay[node0 + i] * w1[jj] + b1[jj]);
    }
    __syncthreads();

    const int j = (tid & 63) * 4;
    const int rg = (tid >> 6) * 4;
    float acc[4][4];
    float4 bv = *(const float4*)&b2[j];
#pragma unroll
    for (int ri = 0; ri < 4; ri++) { acc[ri][0] = bv.x; acc[ri][1] = bv.y; acc[ri][2] = bv.z; acc[ri][3] = bv.w; }

#pragma unroll 2
    for (int k = 0; k < 128; k += 4) {
        float4 x0 = *(const float4*)&g1[rg + 0][k];
        float4 x1 = *(const float4*)&g1[rg + 1][k];
        float4 x2v = *(const float4*)&g1[rg + 2][k];
        float4 x3 = *(const float4*)&g1[rg + 3][k];
        const float* wp = w2 + (size_t)k * 256 + j;
#define PIK(comp, off) { float4 wv = *(const float4*)(wp + (off) * 256); \
    acc[0][0] += x0.comp * wv.x; acc[0][1] += x0.comp * wv.y; acc[0][2] += x0.comp * wv.z; acc[0][3] += x0.comp * wv.w; \
    acc[1][0] += x1.comp * wv.x; acc[1][1] += x1.comp * wv.y; acc[1][2] += x1.comp * wv.z; acc[1][3] += x1.comp * wv.w; \
    acc[2][0] += x2v.comp * wv.x; acc[2][1] += x2v.comp * wv.y; acc[2][2] += x2v.comp * wv.z; acc[2][3] += x2v.comp * wv.w; \
    acc[3][0] += x3.comp * wv.x; acc[3][1] += x3.comp * wv.y; acc[3][2] += x3.comp * wv.z; acc[3][3] += x3.comp * wv.w; }
        PIK(x, 0) PIK(y, 1) PIK(z, 2) PIK(w, 3)
#undef PIK
    }
    float4 avj = *(const float4*)&av[64 + j];
#pragma unroll
    for (int ri = 0; ri < 4; ri++) {
        *(float4*)&outh[(node0 + rg + ri) * HD + j] =
            make_float4(acc[ri][0], acc[ri][1], acc[ri][2], acc[ri][3]);
        float p = acc[ri][0] * avj.x + acc[ri][1] * avj.y + acc[ri][2] * avj.z + acc[ri][3] * avj.w;
#pragma unroll
        for (int off = 1; off < 64; off <<= 1) p += __shfl_xor(p, off);
        if ((tid & 63) == 0) sdot[node0 + rg + ri] = p;
    }
}

// ---------------- per-level kernel: 512 threads; blocks 0..255 gate, 256..511 mod ----------------
__global__ __launch_bounds__(512, 4) void level_kernel(
    const float* __restrict__ prevh, float* __restrict__ nexth,
    const float* __restrict__ sdot_prev, float* __restrict__ sdot_next,
    const float* __restrict__ feat, const float* __restrict__ bitpos,
    const int* __restrict__ srcidx,
    const float* __restrict__ g_w1, const float* __restrict__ g_b1,
    const float* __restrict__ g_w2, const float* __restrict__ g_b2,
    const float* __restrict__ m_w1, const float* __restrict__ m_b1,
    const float* __restrict__ m_w2, const float* __restrict__ m_b2,
    const float* __restrict__ t_w1, const float* __restrict__ t_b1,
    const float* __restrict__ t_w2, const float* __restrict__ t_b2,
    const float* __restrict__ p_w1, const float* __restrict__ p_b1,
    const float* __restrict__ p_w2, const float* __restrict__ p_b2,
    const float* __restrict__ av,
    int level, int apply_relu)
{
    __shared__ float x_lds[TN][292];
    __shared__ float h1_lds[TN][132];
    __shared__ float wbuf[2][4096];     // 32 KB double-buffered weight staging / reduce scratch
    __shared__ int   src_lds[TN * 8];
    __shared__ float bp_lds[TN * 8];
    __shared__ float dstf_lds[TN][32];
    __shared__ float ztt_lds[TN][32];
    __shared__ float alpha_lds[TN * 8];
    __shared__ float xbp_lds[TN];
    __shared__ float av_lds[64];
    __shared__ float tw2av_lds[32];
    __shared__ float pw2av_lds[32];
    __shared__ float bias_av[2];

    const int tid = threadIdx.x;
    const bool is_gate = (blockIdx.x < 256);
    const int node0 = is_gate ? (blockIdx.x * TN) : (PGH + ((int)blockIdx.x - 256) * TN);

    const float* w1 = is_gate ? g_w1 : m_w1;
    const float* b1 = is_gate ? g_b1 : m_b1;
    const float* w2 = is_gate ? g_w2 : m_w2;
    const float* b2 = is_gate ? g_b2 : m_b2;
    const float4* wg1 = (const float4*)w1;
    const float4* wg2 = (const float4*)w2;

    const int ks = tid >> 8;             // K-split half (0/1)
    const int rg = ((tid >> 6) & 3) * 4; // 4-row group (wave-uniform)

    // issue GEMM1 chunk-0 weight loads now; they land during the gather phase
    // chunk layout: [0..2048 floats) = 16 k-rows of half0, [2048..4096) = 16 k-rows of half1
    float4 ta = wg1[tid], tb = wg1[4608 + tid];

    if (tid < TN * 8) src_lds[tid] = srcidx[(level * NP + node0) * 8 + tid];

    if (is_gate) {
        {
            int i = tid >> 5, k = tid & 31;                    // 512 = TN*32 exactly
            x_lds[i][256 + k] = feat[((level + 1) * NP + node0 + i) * FIN + k];
        }
        __syncthreads();
        // gather + per-channel softmax: thread = (half, channel), 4-node chunks
        {
            const int c = tid & 255, sh = (tid >> 8) * 8;
            for (int s0 = 0; s0 < 8; s0 += 4) {
                const int* spA = &src_lds[(sh + s0 + 0) * 8];
                const int* spB = &src_lds[(sh + s0 + 1) * 8];
                const int* spC = &src_lds[(sh + s0 + 2) * 8];
                const int* spD = &src_lds[(sh + s0 + 3) * 8];
                float ma[8], mb[8], mc[8], md[8];
#pragma unroll
                for (int f = 0; f < 8; f++) ma[f] = prevh[spA[f] * HD + c];
#pragma unroll
                for (int f = 0; f < 8; f++) mb[f] = prevh[spB[f] * HD + c];
#pragma unroll
                for (int f = 0; f < 8; f++) mc[f] = prevh[spC[f] * HD + c];
#pragma unroll
                for (int f = 0; f < 8; f++) md[f] = prevh[spD[f] * HD + c];
                float mxa = -1e30f, mxb = -1e30f, mxc = -1e30f, mxd = -1e30f;
#pragma unroll
                for (int f = 0; f < 8; f++) {
                    mxa = fmaxf(mxa, ma[f]); mxb = fmaxf(mxb, mb[f]);
                    mxc = fmaxf(mxc, mc[f]); mxd = fmaxf(mxd, md[f]);
                }
                float sa = 0.f, wsa = 0.f, sb = 0.f, wsb = 0.f;
                float sc = 0.f, wsc = 0.f, sd = 0.f, wsd = 0.f;
#pragma unroll
                for (int f = 0; f < 8; f++) {
                    float ea = __expf(ma[f] - mxa); sa += ea; wsa += ma[f] * ea;
                    float eb = __expf(mb[f] - mxb); sb += eb; wsb += mb[f] * eb;
                    float ec = __expf(mc[f] - mxc); sc += ec; wsc += mc[f] * ec;
                    float ed = __expf(md[f] - mxd); sd += ed; wsd += md[f] * ed;
                }
                x_lds[sh + s0 + 0][c] = wsa / sa;
                x_lds[sh + s0 + 1][c] = wsb / sb;
                x_lds[sh + s0 + 2][c] = wsc / sc;
                x_lds[sh + s0 + 3][c] = wsd / sd;
            }
        }
        __syncthreads();
    } else {
        if (tid < TN * 8) bp_lds[tid] = bitpos[(level * NP + node0) * 8 + tid];
        {
            int i = tid >> 5, k = tid & 31;
            dstf_lds[i][k] = feat[((level + 1) * NP + node0 + i) * FIN + k];
        }
        if (tid < 64) av_lds[tid] = av[tid];
        __syncthreads();

        // ztt = lrelu(dstf @ t_w1 + t_b1): one output per thread (512 = 16*32)
        {
            int i = tid >> 5, jj = tid & 31;
            float a = t_b1[jj];
#pragma unroll 8
            for (int k = 0; k < 32; k++) a += dstf_lds[i][k] * t_w1[k * 32 + jj];
            ztt_lds[i][jj] = lrelu(a);
        }
        // fold attn_vec through second MLP layers (exact linear reassociation)
        if (tid < 32) {
            float s = 0.f;
#pragma unroll 8
            for (int jj = 0; jj < 32; jj++) s += t_w2[tid * 32 + jj] * av_lds[jj];
            tw2av_lds[tid] = s;
        } else if (tid < 64) {
            int k = tid - 32;
            float s = 0.f;
#pragma unroll 8
            for (int jj = 0; jj < 32; jj++) s += p_w2[k * 32 + jj] * av_lds[32 + jj];
            pw2av_lds[k] = s;
        } else if (tid == 64) {
            float s = 0.f;
#pragma unroll 8
            for (int jj = 0; jj < 32; jj++) s += t_b2[jj] * av_lds[jj];
            bias_av[0] = s;
        } else if (tid == 65) {
            float s = 0.f;
#pragma unroll 8
            for (int jj = 0; jj < 32; jj++) s += p_b2[jj] * av_lds[32 + jj];
            bias_av[1] = s;
        }
        __syncthreads();

        // logits + softmax over fanin: first 256 threads, tid = i*16 + f*2 + jg
        if (tid < 256) {
            const int jg = tid & 1, f = (tid >> 1) & 7, i = tid >> 4;
            const float sv = sdot_prev[src_lds[i * 8 + f]];   // hoisted row dot
            const float bpv = bp_lds[i * 8 + f];
            float part = 0.f;
            const int k0 = jg * 16;
#pragma unroll
            for (int k = k0; k < k0 + 16; k++) {
                float h1pk = lrelu(bpv * p_w1[k] + p_b1[k]);
                part += h1pk * pw2av_lds[k];
                part += ztt_lds[i][k] * tw2av_lds[k];
            }
            part += __shfl_xor(part, 1);
            float logit = part + bias_av[0] + bias_av[1] + sv;
            float mx = logit;
            mx = fmaxf(mx, __shfl_xor(mx, 2));
            mx = fmaxf(mx, __shfl_xor(mx, 4));
            mx = fmaxf(mx, __shfl_xor(mx, 8));
            float e = __expf(logit - mx);
            float ssum = e;
            ssum += __shfl_xor(ssum, 2);
            ssum += __shfl_xor(ssum, 4);
            ssum += __shfl_xor(ssum, 8);
            float alpha = e / ssum;
            if (jg == 0) alpha_lds[i * 8 + f] = alpha;
            float ab = alpha * bpv;
            ab += __shfl_xor(ab, 2);
            ab += __shfl_xor(ab, 4);
            ab += __shfl_xor(ab, 8);
            if ((tid & 15) == 0) xbp_lds[i] = ab;
        }
        __syncthreads();

        // neigh_m: thread = (half, channel), 4-node chunks; assemble x
        {
            const int c = tid & 255, sh = (tid >> 8) * 8;
            for (int s0 = 0; s0 < 8; s0 += 4) {
                const int* spA = &src_lds[(sh + s0 + 0) * 8];
                const int* spB = &src_lds[(sh + s0 + 1) * 8];
                const int* spC = &src_lds[(sh + s0 + 2) * 8];
                const int* spD = &src_lds[(sh + s0 + 3) * 8];
                float ma[8], mb[8], mc[8], md[8];
#pragma unroll
                for (int f = 0; f < 8; f++) ma[f] = prevh[spA[f] * HD + c];
#pragma unroll
                for (int f = 0; f < 8; f++) mb[f] = prevh[spB[f] * HD + c];
#pragma unroll
                for (int f = 0; f < 8; f++) mc[f] = prevh[spC[f] * HD + c];
#pragma unroll
                for (int f = 0; f < 8; f++) md[f] = prevh[spD[f] * HD + c];
                const float* apA = &alpha_lds[(sh + s0 + 0) * 8];
                const float* apB = &alpha_lds[(sh + s0 + 1) * 8];
                const float* apC = &alpha_lds[(sh + s0 + 2) * 8];
                const float* apD = &alpha_lds[(sh + s0 + 3) * 8];
                float aa = 0.f, ab2 = 0.f, ac = 0.f, ad = 0.f;
#pragma unroll
                for (int f = 0; f < 8; f++) {
                    aa  += apA[f] * ma[f]; ab2 += apB[f] * mb[f];
                    ac  += apC[f] * mc[f]; ad  += apD[f] * md[f];
                }
                x_lds[sh + s0 + 0][c] = aa;
                x_lds[sh + s0 + 1][c] = ab2;
                x_lds[sh + s0 + 2][c] = ac;
                x_lds[sh + s0 + 3][c] = ad;
            }
        }
        if (tid < TN) x_lds[tid][256] = xbp_lds[tid];
        {
            int i = tid >> 5, k = tid & 31;
            x_lds[i][257 + k] = dstf_lds[i][k];
        }
        __syncthreads();
    }

    // ---------- GEMM1: (16 x K1)@(K1 x 128); R=4, C=2, K-split-2; dbuf staged ----------
    {
        const int j = (tid & 63) * 2;
        float acc[4][2];
        float2 bv = (ks == 0) ? *(const float2*)&b1[j] : make_float2(0.f, 0.f);
#pragma unroll
        for (int ri = 0; ri < 4; ri++) { acc[ri][0] = bv.x; acc[ri][1] = bv.y; }

        for (int c = 0; c < 9; ++c) {            // 9 chunks of (16+16) k-rows = 1024 f4
            float* buf = wbuf[c & 1];
            float4* w4 = (float4*)buf;
            w4[tid] = ta; w4[tid + 512] = tb;    // [0..512)=half0, [512..1024)=half1
            if (c < 8) {
                ta = wg1[(size_t)(c + 1) * 512 + tid];
                tb = wg1[4608 + (size_t)(c + 1) * 512 + tid];
            }
            __syncthreads();
            const float* mybuf = buf + ks * 2048;
            const int kx = ks * 144 + c * 16;
#pragma unroll 2
            for (int k = 0; k < 16; k += 4) {
                float4 x0 = *(const float4*)&x_lds[rg + 0][kx + k];
                float4 x1 = *(const float4*)&x_lds[rg + 1][kx + k];
                float4 x2v = *(const float4*)&x_lds[rg + 2][kx + k];
                float4 x3 = *(const float4*)&x_lds[rg + 3][kx + k];
                const float* wp = mybuf + k * 128 + j;
#define G1K(comp, off) { float2 wv = *(const float2*)(wp + (off) * 128); \
    acc[0][0] += x0.comp * wv.x; acc[0][1] += x0.comp * wv.y; \
    acc[1][0] += x1.comp * wv.x; acc[1][1] += x1.comp * wv.y; \
    acc[2][0] += x2v.comp * wv.x; acc[2][1] += x2v.comp * wv.y; \
    acc[3][0] += x3.comp * wv.x; acc[3][1] += x3.comp * wv.y; }
                G1K(x, 0) G1K(y, 1) G1K(z, 2) G1K(w, 3)
#undef G1K
            }
        }
        // prefetch GEMM2 chunk 0 (lands during the reduction)
        ta = wg2[tid]; tb = wg2[4096 + tid];
        // K-split reduction through wbuf[1] (free: chunk 7's data already consumed)
        __syncthreads();
        if (ks == 1) {
#pragma unroll
            for (int ri = 0; ri < 4; ri++)
                *(float2*)&wbuf[1][(rg + ri) * 128 + j] = make_float2(acc[ri][0], acc[ri][1]);
        }
        __syncthreads();
        if (ks == 0) {
#pragma unroll
            for (int ri = 0; ri < 4; ri++) {
                float2 pv = *(const float2*)&wbuf[1][(rg + ri) * 128 + j];
                float a0 = acc[ri][0] + pv.x, a1 = acc[ri][1] + pv.y;
                if (!is_gate) {
                    float xb = x_lds[rg + ri][288];
                    a0 += xb * w1[288 * 128 + j];
                    a1 += xb * w1[288 * 128 + j + 1];
                }
                *(float2*)&h1_lds[rg + ri][j] = make_float2(lrelu(a0), lrelu(a1));
            }
        }
    }
    __syncthreads();

    // ---------- GEMM2: (16 x 128)@(128 x 256); R=4, C=4, K-split-2; dbuf staged ----------
    {
        const int j = (tid & 63) * 4;
        float acc[4][4];
        float4 bv = (ks == 0) ? *(const float4*)&b2[j] : make_float4(0.f, 0.f, 0.f, 0.f);
#pragma unroll
        for (int ri = 0; ri < 4; ri++) { acc[ri][0] = bv.x; acc[ri][1] = bv.y; acc[ri][2] = bv.z; acc[ri][3] = bv.w; }

        for (int c = 0; c < 8; ++c) {            // 8 chunks of (8+8) k-rows = 1024 f4
            float* buf = wbuf[c & 1];
            float4* w4 = (float4*)buf;
            w4[tid] = ta; w4[tid + 512] = tb;
            if (c < 7) {
                ta = wg2[(size_t)(c + 1) * 512 + tid];
                tb = wg2[4096 + (size_t)(c + 1) * 512 + tid];
            }
            __syncthreads();
            const float* mybuf = buf + ks * 2048;
            const int kx = ks * 64 + c * 8;
#pragma unroll 2
            for (int k = 0; k < 8; k += 4) {
                float4 x0 = *(const float4*)&h1_lds[rg + 0][kx + k];
                float4 x1 = *(const float4*)&h1_lds[rg + 1][kx + k];
                float4 x2v = *(const float4*)&h1_lds[rg + 2][kx + k];
                float4 x3 = *(const float4*)&h1_lds[rg + 3][kx + k];
                const float* wp = mybuf + k * 256 + j;
#define G2K(comp, off) { float4 wv = *(const float4*)(wp + (off) * 256); \
    acc[0][0] += x0.comp * wv.x; acc[0][1] += x0.comp * wv.y; acc[0][2] += x0.comp * wv.z; acc[0][3] += x0.comp * wv.w; \
    acc[1][0] += x1.comp * wv.x; acc[1][1] += x1.comp * wv.y; acc[1][2] += x1.comp * wv.z; acc[1][3] += x1.comp * wv.w; \
    acc[2][0] += x2v.comp * wv.x; acc[2][1] += x2v.comp * wv.y; acc[2][2] += x2v.comp * wv.z; acc[2][3] += x2v.comp * wv.w; \
    acc[3][0] += x3.comp * wv.x; acc[3][1] += x3.comp * wv.y; acc[3][2] += x3.comp * wv.z; acc[3][3] += x3.comp * wv.w; }
                G2K(x, 0) G2K(y, 1) G2K(z, 2) G2K(w, 3)
#undef G2K
            }
        }
        // reduction through wbuf[0] (free: chunk 6's data already consumed)
        __syncthreads();
        if (ks == 1) {
#pragma unroll
            for (int ri = 0; ri < 4; ri++)
                *(float4*)&wbuf[0][(rg + ri) * 256 + j] =
                    make_float4(acc[ri][0], acc[ri][1], acc[ri][2], acc[ri][3]);
        }
        __syncthreads();
        if (ks == 0) {
            float4 avj = *(const float4*)&av[64 + j];
#pragma unroll
            for (int ri = 0; ri < 4; ri++) {
                float4 pv = *(const float4*)&wbuf[0][(rg + ri) * 256 + j];
                float a0 = acc[ri][0] + pv.x, a1 = acc[ri][1] + pv.y;
                float a2 = acc[ri][2] + pv.z, a3 = acc[ri][3] + pv.w;
                if (apply_relu) {
                    a0 = fmaxf(a0, 0.f); a1 = fmaxf(a1, 0.f);
                    a2 = fmaxf(a2, 0.f); a3 = fmaxf(a3, 0.f);
                }
                *(float4*)&nexth[(node0 + rg + ri) * HD + j] = make_float4(a0, a1, a2, a3);
                float p = a0 * avj.x + a1 * avj.y + a2 * avj.z + a3 * avj.w;
#pragma unroll
                for (int off = 1; off < 64; off <<= 1) p += __shfl_xor(p, off);
                if ((tid & 63) == 0) sdot_next[node0 + rg + ri] = p;
            }
        }
    }
}

// ---------------- final kernel: 512 threads; glob mlp + concat + out mlp (fused) ----------------
__global__ __launch_bounds__(512, 4) void final_kernel(
    const float* __restrict__ prevh, const float* __restrict__ pofeat,
    const float* __restrict__ gl_w1, const float* __restrict__ gl_b1,
    const float* __restrict__ gl_w2, const float* __restrict__ gl_b2,
    const float* __restrict__ o_w1, const float* __restrict__ o_b1,
    const float* __restrict__ o_w2, const float* __restrict__ o_b2,
    float* __restrict__ out)
{
    __shared__ float x2[TN][516];
    __shared__ float g1[TN][132];
    __shared__ float wbuf[2][4096];
    __shared__ float ow2_lds[256];

    const int tid = threadIdx.x;
    const int node0 = blockIdx.x * TN;
    const int ks = tid >> 8;
    const int rg = ((tid >> 6) & 3) * 4;
    const int j = (tid & 63) * 4;

    const float4* wgl = (const float4*)gl_w2;
    const float4* wo  = (const float4*)o_w1;
    float4 ta = wgl[tid], tb = wgl[4096 + tid];

    for (int q = tid; q < TN * 64; q += 512) {
        int i = q >> 6, c4 = (q & 63) * 4;
        *(float4*)&x2[i][c4] = *(const float4*)&prevh[(node0 + i) * HD + c4];
    }
    for (int t = tid; t < TN * 128; t += 512) {
        int i = t >> 7, jj = t & 127;
        g1[i][jj] = lrelu(pofeat[node0 + i] * gl_w1[jj] + gl_b1[jj]);
    }
    if (tid < 256) ow2_lds[tid] = o_w2[tid];
    __syncthreads();

    // glob layer 2: (16x128)@(128x256) -> x2 cols 256..511; R=4,C=4,Ksplit2; dbuf
    {
        float acc[4][4];
        float4 bv = (ks == 0) ? *(const float4*)&gl_b2[j] : make_float4(0.f, 0.f, 0.f, 0.f);
#pragma unroll
        for (int ri = 0; ri < 4; ri++) { acc[ri][0] = bv.x; acc[ri][1] = bv.y; acc[ri][2] = bv.z; acc[ri][3] = bv.w; }
        for (int c = 0; c < 8; ++c) {
            float* buf = wbuf[c & 1];
            float4* w4 = (float4*)buf;
            w4[tid] = ta; w4[tid + 512] = tb;
            if (c < 7) {
                ta = wgl[(size_t)(c + 1) * 512 + tid];
                tb = wgl[4096 + (size_t)(c + 1) * 512 + tid];
            } else {
                ta = wo[tid]; tb = wo[16384 + tid];   // prefetch out1 chunk 0
            }
            __syncthreads();
            const float* mybuf = buf + ks * 2048;
            const int kx = ks * 64 + c * 8;
#pragma unroll 2
            for (int k = 0; k < 8; k += 4) {
                float4 x0 = *(const float4*)&g1[rg + 0][kx + k];
                float4 x1 = *(const float4*)&g1[rg + 1][kx + k];
                float4 x2v = *(const float4*)&g1[rg + 2][kx + k];
                float4 x3 = *(const float4*)&g1[rg + 3][kx + k];
                const float* wp = mybuf + k * 256 + j;
#define GLK(comp, off) { float4 wv = *(const float4*)(wp + (off) * 256); \
    acc[0][0] += x0.comp * wv.x; acc[0][1] += x0.comp * wv.y; acc[0][2] += x0.comp * wv.z; acc[0][3] += x0.comp * wv.w; \
    acc[1][0] += x1.comp * wv.x; acc[1][1] += x1.comp * wv.y; acc[1][2] += x1.comp * wv.z; acc[1][3] += x1.comp * wv.w; \
    acc[2][0] += x2v.comp * wv.x; acc[2][1] += x2v.comp * wv.y; acc[2][2] += x2v.comp * wv.z; acc[2][3] += x2v.comp * wv.w; \
    acc[3][0] += x3.comp * wv.x; acc[3][1] += x3.comp * wv.y; acc[3][2] += x3.comp * wv.z; acc[3][3] += x3.comp * wv.w; }
                GLK(x, 0) GLK(y, 1) GLK(z, 2) GLK(w, 3)
#undef GLK
            }
        }
        __syncthreads();
        if (ks == 1) {
#pragma unroll
            for (int ri = 0; ri < 4; ri++)
                *(float4*)&wbuf[0][(rg + ri) * 256 + j] =
                    make_float4(acc[ri][0], acc[ri][1], acc[ri][2], acc[ri][3]);
        }
        __syncthreads();
        if (ks == 0) {
#pragma unroll
            for (int ri = 0; ri < 4; ri++) {
                float4 pv = *(const float4*)&wbuf[0][(rg + ri) * 256 + j];
                *(float4*)&x2[rg + ri][256 + j] =
                    make_float4(acc[ri][0] + pv.x, acc[ri][1] + pv.y,
                                acc[ri][2] + pv.z, acc[ri][3] + pv.w);
            }
        }
    }
    __syncthreads();

    // out layer 1: (16x512)@(512x256); R=4,C=4,Ksplit2 (256 k each); fused out layer 2
    {
        float acc[4][4];
        float4 bv = (ks == 0) ? *(const float4*)&o_b1[j] : make_float4(0.f, 0.f, 0.f, 0.f);
#pragma unroll
        for (int ri = 0; ri < 4; ri++) { acc[ri][0] = bv.x; acc[ri][1] = bv.y; acc[ri][2] = bv.z; acc[ri][3] = bv.w; }
        for (int c = 0; c < 32; ++c) {
            float* buf = wbuf[c & 1];
            float4* w4 = (float4*)buf;
            w4[tid] = ta; w4[tid + 512] = tb;
            if (c < 31) {
                ta = wo[(size_t)(c + 1) * 512 + tid];
                tb = wo[16384 + (size_t)(c + 1) * 512 + tid];
            }
            __syncthreads();
            const float* mybuf = buf + ks * 2048;
            const int kx = ks * 256 + c * 8;
#pragma unroll 2
            for (int k = 0; k < 8; k += 4) {
                float4 x0 = *(const float4*)&x2[rg + 0][kx + k];
                float4 x1 = *(const float4*)&x2[rg + 1][kx + k];
                float4 x2v = *(const float4*)&x2[rg + 2][kx + k];
                float4 x3 = *(const float4*)&x2[rg + 3][kx + k];
                const float* wp = mybuf + k * 256 + j;
#define O1K(comp, off) { float4 wv = *(const float4*)(wp + (off) * 256); \
    acc[0][0] += x0.comp * wv.x; acc[0][1] += x0.comp * wv.y; acc[0][2] += x0.comp * wv.z; acc[0][3] += x0.comp * wv.w; \
    acc[1][0] += x1.comp * wv.x; acc[1][1] += x1.comp * wv.y; acc[1][2] += x1.comp * wv.z; acc[1][3] += x1.comp * wv.w; \
    acc[2][0] += x2v.comp * wv.x; acc[2][1] += x2v.comp * wv.y; acc[2][2] += x2v.comp * wv.z; acc[2][3] += x2v.comp * wv.w; \
    acc[3][0] += x3.comp * wv.x; acc[3][1] += x3.comp * wv.y; acc[3][2] += x3.comp * wv.z; acc[3][3] += x3.comp * wv.w; }
                O1K(x, 0) O1K(y, 1) O1K(z, 2) O1K(w, 3)
#undef O1K
            }
        }
        __syncthreads();
        if (ks == 1) {
#pragma unroll
            for (int ri = 0; ri < 4; ri++)
                *(float4*)&wbuf[0][(rg + ri) * 256 + j] =
                    make_float4(acc[ri][0], acc[ri][1], acc[ri][2], acc[ri][3]);
        }
        __syncthreads();
        if (ks == 0) {
            float w0 = ow2_lds[j], w1v = ow2_lds[j + 1], w2v = ow2_lds[j + 2], w3v = ow2_lds[j + 3];
            float ob = o_b2[0];
#pragma unroll
            for (int ri = 0; ri < 4; ri++) {
                float4 pv = *(const float4*)&wbuf[0][(rg + ri) * 256 + j];
                float p = lrelu(acc[ri][0] + pv.x) * w0 + lrelu(acc[ri][1] + pv.y) * w1v
                        + lrelu(acc[ri][2] + pv.z) * w2v + lrelu(acc[ri][3] + pv.w) * w3v;
#pragma unroll
                for (int off = 1; off < 64; off <<= 1) p += __shfl_xor(p, off);
                if ((tid & 63) == 0) out[node0 + rg + ri] = p + ob;
            }
        }
    }
}

extern "C" void kernel_launch(void* const* d_in, const int* in_sizes, int n_in,
                              void* d_out, int out_size, void* d_ws, size_t ws_size,
                              hipStream_t stream)
{
    const float* delay    = (const float*)d_in[0];
    const float* feat     = (const float*)d_in[1];
    const float* bitpos   = (const float*)d_in[2];
    const float* pofeat   = (const float*)d_in[3];
    const int*   srcidx   = (const int*)  d_in[4];
    const float* pi_w1    = (const float*)d_in[5];
    const float* pi_b1    = (const float*)d_in[6];
    const float* pi_w2    = (const float*)d_in[7];
    const float* pi_b2    = (const float*)d_in[8];
    const float* gate_w1  = (const float*)d_in[9];
    const float* gate_b1  = (const float*)d_in[10];
    const float* gate_w2  = (const float*)d_in[11];
    const float* gate_b2  = (const float*)d_in[12];
    const float* mod_w1   = (const float*)d_in[13];
    const float* mod_b1   = (const float*)d_in[14];
    const float* mod_w2   = (const float*)d_in[15];
    const float* mod_b2   = (const float*)d_in[16];
    const float* type_w1  = (const float*)d_in[17];
    const float* type_b1  = (const float*)d_in[18];
    const float* type_w2  = (const float*)d_in[19];
    const float* type_b2  = (const float*)d_in[20];
    const float* pos_w1   = (const float*)d_in[21];
    const float* pos_b1   = (const float*)d_in[22];
    const float* pos_w2   = (const float*)d_in[23];
    const float* pos_b2   = (const float*)d_in[24];
    const float* attn_vec = (const float*)d_in[25];
    const float* glob_w1  = (const float*)d_in[26];
    const float* glob_b1  = (const float*)d_in[27];
    const float* glob_w2  = (const float*)d_in[28];
    const float* glob_b2  = (const float*)d_in[29];
    const float* out_w1   = (const float*)d_in[30];
    const float* out_b1   = (const float*)d_in[31];
    const float* out_w2   = (const float*)d_in[32];
    const float* out_b2   = (const float*)d_in[33];

    float* buf0 = (float*)d_ws;
    float* buf1 = buf0 + (size_t)NP * HD;
    float* sd0  = buf1 + (size_t)NP * HD;
    float* sd1  = sd0 + NP;

    pi_kernel<<<NP / TN, 256, 0, stream>>>(delay, pi_w1, pi_b1, pi_w2, pi_b2,
                                           attn_vec, buf0, sd0);

    for (int l = 0; l < NLVL; l++) {
        float* pv = (l & 1) ? buf1 : buf0;
        float* nx = (l & 1) ? buf0 : buf1;
        float* sp = (l & 1) ? sd1 : sd0;
        float* sn = (l & 1) ? sd0 : sd1;
        level_kernel<<<NP / TN, 512, 0, stream>>>(
            pv, nx, sp, sn, feat, bitpos, srcidx,
            gate_w1, gate_b1, gate_w2, gate_b2,
            mod_w1, mod_b1, mod_w2, mod_b2,
            type_w1, type_b1, type_w2, type_b2,
            pos_w1, pos_b1, pos_w2, pos_b2,
            attn_vec, l, (l != NLVL - 1) ? 1 : 0);
    }

    final_kernel<<<NP / TN, 512, 0, stream>>>(
        buf1, pofeat,
        glob_w1, glob_b1, glob_w2, glob_b2,
        out_w1, out_b1, out_w2, out_b2,
        (float*)d_out);
}

// Round 13
// 347.201 us; speedup vs baseline: 1.9083x; 1.6367x over previous
//
#include <hip/hip_runtime.h>
#include <math.h>

#define HD   256
#define FIN  32
#define NP   8192
#define PGH  4096
#define NLVL 15
#define TN   16

typedef __attribute__((ext_vector_type(4))) short v4s;
typedef __attribute__((ext_vector_type(8))) short v8s;
typedef __attribute__((ext_vector_type(4))) float v4f;

#define MFMA __builtin_amdgcn_mfma_f32_16x16x32_bf16

// packed bf16 hi/lo fragment-layout weights (written by prep_kernel each launch)
// bases (ushorts): g_w1 0 (73728), m_w1 73728, g_w2 147456, m_w2 212992, gl_w2 278528, o_w1 344064 (262144)
__device__ __align__(16) unsigned short g_wpk[606208];

__device__ __forceinline__ float lrelu(float x) { return x > 0.f ? x : 0.1f * x; }

__device__ __forceinline__ void cvt_duo(float v, unsigned short& hi, unsigned short& lo) {
    unsigned int u = __float_as_uint(v);
    unsigned int r = u + 0x7fffu + ((u >> 16) & 1u);       // RNE to bf16
    hi = (unsigned short)(r >> 16);
    float d = v - __uint_as_float((unsigned int)hi << 16);
    unsigned int u2 = __float_as_uint(d);
    unsigned int r2 = u2 + 0x7fffu + ((u2 >> 16) & 1u);
    lo = (unsigned short)(r2 >> 16);
}

__device__ __forceinline__ v8s pack8(v4s a, v4s b) {
    v8s r; r[0]=a[0]; r[1]=a[1]; r[2]=a[2]; r[3]=a[3]; r[4]=b[0]; r[5]=b[1]; r[6]=b[2]; r[7]=b[3];
    return r;
}

// ---------------- prep: pack weights to bf16 hi/lo MFMA-fragment layout ----------------
__global__ __launch_bounds__(256) void prep_kernel(
    const float* __restrict__ gw1, const float* __restrict__ mw1,
    const float* __restrict__ gw2, const float* __restrict__ mw2,
    const float* __restrict__ glw2, const float* __restrict__ ow1)
{
    int t = blockIdx.x * 256 + threadIdx.x;
    const float* src; int base, N, idx;
    if (t < 36864)       { src = gw1;  base = 0;      N = 128; idx = t; }
    else if (t < 73728)  { src = mw1;  base = 73728;  N = 128; idx = t - 36864; }
    else if (t < 106496) { src = gw2;  base = 147456; N = 256; idx = t - 73728; }
    else if (t < 139264) { src = mw2;  base = 212992; N = 256; idx = t - 106496; }
    else if (t < 172032) { src = glw2; base = 278528; N = 256; idx = t - 139264; }
    else if (t < 303104) { src = ow1;  base = 344064; N = 256; idx = t - 172032; }
    else return;
    int sh = (N == 128) ? 7 : 8;
    int k = idx >> sh, col = idx & (N - 1);
    float v = src[idx];
    unsigned short hi, lo; cvt_duo(v, hi, lo);
    int ks = k >> 5, kk = k & 31;
    int ch = col >> 7, cc = col & 127, ct = cc >> 4;
    int nch = N >> 7;
    int l = ((kk & 15) >> 2) * 16 + (cc & 15);
    int w = (kk & 3) + (kk >> 4) * 4;
    int off = ((ks * nch + ch) * 2) * 4096 + ct * 512 + l * 8 + w;
    g_wpk[base + off] = hi;
    g_wpk[base + off + 4096] = lo;
}

// ---------------- pi kernel: prev_h = mlp(delay), + sdot epilogue (fp32) ----------------
__global__ __launch_bounds__(256) void pi_kernel(
    const float* __restrict__ delay,
    const float* __restrict__ w1, const float* __restrict__ b1,
    const float* __restrict__ w2, const float* __restrict__ b2,
    const float* __restrict__ av,
    float* __restrict__ outh, float* __restrict__ sdot)
{
    __shared__ float g1[TN][132];
    const int tid = threadIdx.x;
    const int node0 = blockIdx.x * TN;

    for (int t = tid; t < TN * 128; t += 256) {
        int i = t >> 7, jj = t & 127;
        g1[i][jj] = lrelu(delay[node0 + i] * w1[jj] + b1[jj]);
    }
    __syncthreads();

    const int j = (tid & 63) * 4;
    const int rg = (tid >> 6) * 4;
    float acc[4][4];
    float4 bv = *(const float4*)&b2[j];
#pragma unroll
    for (int ri = 0; ri < 4; ri++) { acc[ri][0] = bv.x; acc[ri][1] = bv.y; acc[ri][2] = bv.z; acc[ri][3] = bv.w; }

#pragma unroll 2
    for (int k = 0; k < 128; k += 4) {
        float4 x0 = *(const float4*)&g1[rg + 0][k];
        float4 x1 = *(const float4*)&g1[rg + 1][k];
        float4 x2v = *(const float4*)&g1[rg + 2][k];
        float4 x3 = *(const float4*)&g1[rg + 3][k];
        const float* wp = w2 + (size_t)k * 256 + j;
#define PIK(comp, off) { float4 wv = *(const float4*)(wp + (off) * 256); \
    acc[0][0] += x0.comp * wv.x; acc[0][1] += x0.comp * wv.y; acc[0][2] += x0.comp * wv.z; acc[0][3] += x0.comp * wv.w; \
    acc[1][0] += x1.comp * wv.x; acc[1][1] += x1.comp * wv.y; acc[1][2] += x1.comp * wv.z; acc[1][3] += x1.comp * wv.w; \
    acc[2][0] += x2v.comp * wv.x; acc[2][1] += x2v.comp * wv.y; acc[2][2] += x2v.comp * wv.z; acc[2][3] += x2v.comp * wv.w; \
    acc[3][0] += x3.comp * wv.x; acc[3][1] += x3.comp * wv.y; acc[3][2] += x3.comp * wv.z; acc[3][3] += x3.comp * wv.w; }
        PIK(x, 0) PIK(y, 1) PIK(z, 2) PIK(w, 3)
#undef PIK
    }
    float4 avj = *(const float4*)&av[64 + j];
#pragma unroll
    for (int ri = 0; ri < 4; ri++) {
        *(float4*)&outh[(node0 + rg + ri) * HD + j] =
            make_float4(acc[ri][0], acc[ri][1], acc[ri][2], acc[ri][3]);
        float p = acc[ri][0] * avj.x + acc[ri][1] * avj.y + acc[ri][2] * avj.z + acc[ri][3] * avj.w;
#pragma unroll
        for (int off = 1; off < 64; off <<= 1) p += __shfl_xor(p, off);
        if ((tid & 63) == 0) sdot[node0 + rg + ri] = p;
    }
}

// ---------------- per-level kernel: 512 threads; blocks 0..255 gate, 256..511 mod ----------------
__global__ __launch_bounds__(512, 4) void level_kernel(
    const float* __restrict__ prevh, float* __restrict__ nexth,
    const float* __restrict__ sdot_prev, float* __restrict__ sdot_next,
    const float* __restrict__ feat, const float* __restrict__ bitpos,
    const int* __restrict__ srcidx,
    const float* __restrict__ g_w1, const float* __restrict__ g_b1,
    const float* __restrict__ g_b2,
    const float* __restrict__ m_w1, const float* __restrict__ m_b1,
    const float* __restrict__ m_b2,
    const float* __restrict__ t_w1, const float* __restrict__ t_b1,
    const float* __restrict__ t_w2, const float* __restrict__ t_b2,
    const float* __restrict__ p_w1, const float* __restrict__ p_b1,
    const float* __restrict__ p_w2, const float* __restrict__ p_b2,
    const float* __restrict__ av,
    int level, int apply_relu)
{
    __shared__ unsigned short xh_lds[16 * 296];
    __shared__ unsigned short xl_lds[16 * 296];
    __shared__ unsigned short h1h_lds[16 * 136];
    __shared__ unsigned short h1l_lds[16 * 136];
    __shared__ float wbuf[2][4096];       // 2 x 16 KB staging
    __shared__ int   src_lds[128];
    __shared__ float bp_lds[128];
    __shared__ float dstf_lds[16][32];
    __shared__ float ztt_lds[16][32];
    __shared__ float alpha_lds[128];
    __shared__ float xbp_lds[16];
    __shared__ float av_lds[64];
    __shared__ float tw2av_lds[32];
    __shared__ float pw2av_lds[32];
    __shared__ float bias_av[2];
    __shared__ float red_lds[16][8];

    const int tid = threadIdx.x;
    const bool is_gate = (blockIdx.x < 256);
    const int node0 = is_gate ? (blockIdx.x * TN) : (PGH + ((int)blockIdx.x - 256) * TN);

    const float* w1 = is_gate ? g_w1 : m_w1;
    const float* b1 = is_gate ? g_b1 : m_b1;
    const float* b2 = is_gate ? g_b2 : m_b2;
    const float4* gpk1 = (const float4*)(g_wpk + (is_gate ? 0 : 73728));
    const float4* gpk2 = (const float4*)(g_wpk + (is_gate ? 147456 : 212992));

    // issue GEMM1 stage-0 weight loads now; land during gather
    float4 ta = gpk1[tid], tb = gpk1[512 + tid];

    if (tid < 128) src_lds[tid] = srcidx[(level * NP + node0) * 8 + tid];

    if (is_gate) {
        {
            int i = tid >> 5, k = tid & 31;
            float v = feat[((level + 1) * NP + node0 + i) * FIN + k];
            unsigned short h, l; cvt_duo(v, h, l);
            xh_lds[i * 296 + 256 + k] = h; xl_lds[i * 296 + 256 + k] = l;
        }
        __syncthreads();
        // gather + per-channel softmax: thread = (half, channel), 4-node chunks
        {
            const int c = tid & 255, sh = (tid >> 8) * 8;
            for (int s0 = 0; s0 < 8; s0 += 4) {
                const int* spA = &src_lds[(sh + s0 + 0) * 8];
                const int* spB = &src_lds[(sh + s0 + 1) * 8];
                const int* spC = &src_lds[(sh + s0 + 2) * 8];
                const int* spD = &src_lds[(sh + s0 + 3) * 8];
                float ma[8], mb[8], mc[8], md[8];
#pragma unroll
                for (int f = 0; f < 8; f++) ma[f] = prevh[spA[f] * HD + c];
#pragma unroll
                for (int f = 0; f < 8; f++) mb[f] = prevh[spB[f] * HD + c];
#pragma unroll
                for (int f = 0; f < 8; f++) mc[f] = prevh[spC[f] * HD + c];
#pragma unroll
                for (int f = 0; f < 8; f++) md[f] = prevh[spD[f] * HD + c];
                float mxa = -1e30f, mxb = -1e30f, mxc = -1e30f, mxd = -1e30f;
#pragma unroll
                for (int f = 0; f < 8; f++) {
                    mxa = fmaxf(mxa, ma[f]); mxb = fmaxf(mxb, mb[f]);
                    mxc = fmaxf(mxc, mc[f]); mxd = fmaxf(mxd, md[f]);
                }
                float sa = 0.f, wsa = 0.f, sb = 0.f, wsb = 0.f;
                float sc = 0.f, wsc = 0.f, sd = 0.f, wsd = 0.f;
#pragma unroll
                for (int f = 0; f < 8; f++) {
                    float ea = __expf(ma[f] - mxa); sa += ea; wsa += ma[f] * ea;
                    float eb = __expf(mb[f] - mxb); sb += eb; wsb += mb[f] * eb;
                    float ec = __expf(mc[f] - mxc); sc += ec; wsc += mc[f] * ec;
                    float ed = __expf(md[f] - mxd); sd += ed; wsd += md[f] * ed;
                }
                unsigned short h, l;
                cvt_duo(wsa / sa, h, l); xh_lds[(sh+s0+0)*296 + c] = h; xl_lds[(sh+s0+0)*296 + c] = l;
                cvt_duo(wsb / sb, h, l); xh_lds[(sh+s0+1)*296 + c] = h; xl_lds[(sh+s0+1)*296 + c] = l;
                cvt_duo(wsc / sc, h, l); xh_lds[(sh+s0+2)*296 + c] = h; xl_lds[(sh+s0+2)*296 + c] = l;
                cvt_duo(wsd / sd, h, l); xh_lds[(sh+s0+3)*296 + c] = h; xl_lds[(sh+s0+3)*296 + c] = l;
            }
        }
        __syncthreads();
    } else {
        if (tid < 128) bp_lds[tid] = bitpos[(level * NP + node0) * 8 + tid];
        {
            int i = tid >> 5, k = tid & 31;
            float v = feat[((level + 1) * NP + node0 + i) * FIN + k];
            dstf_lds[i][k] = v;
            unsigned short h, l; cvt_duo(v, h, l);
            xh_lds[i * 296 + 257 + k] = h; xl_lds[i * 296 + 257 + k] = l;
        }
        if (tid < 64) av_lds[tid] = av[tid];
        __syncthreads();

        // ztt = lrelu(dstf @ t_w1 + t_b1)
        {
            int i = tid >> 5, jj = tid & 31;
            float a = t_b1[jj];
#pragma unroll 8
            for (int k = 0; k < 32; k++) a += dstf_lds[i][k] * t_w1[k * 32 + jj];
            ztt_lds[i][jj] = lrelu(a);
        }
        // fold attn_vec through second MLP layers (exact linear reassociation)
        if (tid < 32) {
            float s = 0.f;
#pragma unroll 8
            for (int jj = 0; jj < 32; jj++) s += t_w2[tid * 32 + jj] * av_lds[jj];
            tw2av_lds[tid] = s;
        } else if (tid < 64) {
            int k = tid - 32;
            float s = 0.f;
#pragma unroll 8
            for (int jj = 0; jj < 32; jj++) s += p_w2[k * 32 + jj] * av_lds[32 + jj];
            pw2av_lds[k] = s;
        } else if (tid == 64) {
            float s = 0.f;
#pragma unroll 8
            for (int jj = 0; jj < 32; jj++) s += t_b2[jj] * av_lds[jj];
            bias_av[0] = s;
        } else if (tid == 65) {
            float s = 0.f;
#pragma unroll 8
            for (int jj = 0; jj < 32; jj++) s += p_b2[jj] * av_lds[32 + jj];
            bias_av[1] = s;
        }
        __syncthreads();

        // logits + softmax over fanin (hoisted sdot): first 256 threads, tid = i*16 + f*2 + jg
        if (tid < 256) {
            const int jg = tid & 1, f = (tid >> 1) & 7, i = tid >> 4;
            const float sv = sdot_prev[src_lds[i * 8 + f]];
            const float bpv = bp_lds[i * 8 + f];
            float part = 0.f;
            const int k0 = jg * 16;
#pragma unroll
            for (int k = k0; k < k0 + 16; k++) {
                float h1pk = lrelu(bpv * p_w1[k] + p_b1[k]);
                part += h1pk * pw2av_lds[k];
                part += ztt_lds[i][k] * tw2av_lds[k];
            }
            part += __shfl_xor(part, 1);
            float logit = part + bias_av[0] + bias_av[1] + sv;
            float mx = logit;
            mx = fmaxf(mx, __shfl_xor(mx, 2));
            mx = fmaxf(mx, __shfl_xor(mx, 4));
            mx = fmaxf(mx, __shfl_xor(mx, 8));
            float e = __expf(logit - mx);
            float ssum = e;
            ssum += __shfl_xor(ssum, 2);
            ssum += __shfl_xor(ssum, 4);
            ssum += __shfl_xor(ssum, 8);
            float alpha = e / ssum;
            if (jg == 0) alpha_lds[i * 8 + f] = alpha;
            float ab = alpha * bpv;
            ab += __shfl_xor(ab, 2);
            ab += __shfl_xor(ab, 4);
            ab += __shfl_xor(ab, 8);
            if ((tid & 15) == 0) xbp_lds[i] = ab;
        }
        __syncthreads();

        // neigh_m: thread = (half, channel), 4-node chunks; write x duo
        {
            const int c = tid & 255, sh = (tid >> 8) * 8;
            for (int s0 = 0; s0 < 8; s0 += 4) {
                const int* spA = &src_lds[(sh + s0 + 0) * 8];
                const int* spB = &src_lds[(sh + s0 + 1) * 8];
                const int* spC = &src_lds[(sh + s0 + 2) * 8];
                const int* spD = &src_lds[(sh + s0 + 3) * 8];
                float ma[8], mb[8], mc[8], md[8];
#pragma unroll
                for (int f = 0; f < 8; f++) ma[f] = prevh[spA[f] * HD + c];
#pragma unroll
                for (int f = 0; f < 8; f++) mb[f] = prevh[spB[f] * HD + c];
#pragma unroll
                for (int f = 0; f < 8; f++) mc[f] = prevh[spC[f] * HD + c];
#pragma unroll
                for (int f = 0; f < 8; f++) md[f] = prevh[spD[f] * HD + c];
                const float* apA = &alpha_lds[(sh + s0 + 0) * 8];
                const float* apB = &alpha_lds[(sh + s0 + 1) * 8];
                const float* apC = &alpha_lds[(sh + s0 + 2) * 8];
                const float* apD = &alpha_lds[(sh + s0 + 3) * 8];
                float aa = 0.f, ab2 = 0.f, ac = 0.f, ad = 0.f;
#pragma unroll
                for (int f = 0; f < 8; f++) {
                    aa  += apA[f] * ma[f]; ab2 += apB[f] * mb[f];
                    ac  += apC[f] * mc[f]; ad  += apD[f] * md[f];
                }
                unsigned short h, l;
                cvt_duo(aa,  h, l); xh_lds[(sh+s0+0)*296 + c] = h; xl_lds[(sh+s0+0)*296 + c] = l;
                cvt_duo(ab2, h, l); xh_lds[(sh+s0+1)*296 + c] = h; xl_lds[(sh+s0+1)*296 + c] = l;
                cvt_duo(ac,  h, l); xh_lds[(sh+s0+2)*296 + c] = h; xl_lds[(sh+s0+2)*296 + c] = l;
                cvt_duo(ad,  h, l); xh_lds[(sh+s0+3)*296 + c] = h; xl_lds[(sh+s0+3)*296 + c] = l;
            }
        }
        if (tid < TN) {
            unsigned short h, l; cvt_duo(xbp_lds[tid], h, l);
            xh_lds[tid * 296 + 256] = h; xl_lds[tid * 296 + 256] = l;
        }
        __syncthreads();
    }

    const int lane = tid & 63, wv = tid >> 6;
    const int lr = lane & 15, lg = lane >> 4;

    // ---------- GEMM1 (MFMA bf16x3): (16 x 288) @ (288 x 128), k=288 extra in epilogue ----------
    {
        const unsigned short* xrh = xh_lds + lr * 296 + 4 * lg;
        const unsigned short* xrl = xl_lds + lr * 296 + 4 * lg;
        const int colg = wv * 16 + lr;
        float bb = b1[colg];
        v4f acc = {bb, bb, bb, bb};
        for (int s = 0; s < 9; ++s) {
            float4* w4 = (float4*)wbuf[s & 1];
            w4[tid] = ta; w4[tid + 512] = tb;
            if (s < 8) { ta = gpk1[(s + 1) * 1024 + tid]; tb = gpk1[(s + 1) * 1024 + 512 + tid]; }
            __syncthreads();
            const unsigned short* wb = (const unsigned short*)wbuf[s & 1];
            int k0 = s * 32;
            v8s Ah = pack8(*(const v4s*)(xrh + k0), *(const v4s*)(xrh + k0 + 16));
            v8s Al = pack8(*(const v4s*)(xrl + k0), *(const v4s*)(xrl + k0 + 16));
            v8s Bh = *(const v8s*)(wb + wv * 512 + lane * 8);
            v8s Bl = *(const v8s*)(wb + 4096 + wv * 512 + lane * 8);
            acc = MFMA(Ah, Bh, acc, 0, 0, 0);
            acc = MFMA(Ah, Bl, acc, 0, 0, 0);
            acc = MFMA(Al, Bh, acc, 0, 0, 0);
        }
        ta = gpk2[tid]; tb = gpk2[512 + tid];     // prefetch GEMM2 stage 0
        float w288 = is_gate ? 0.f : w1[288 * 128 + colg];
#pragma unroll
        for (int r = 0; r < 4; ++r) {
            int row = lg * 4 + r;
            float v = acc[r];
            if (!is_gate) v += dstf_lds[row][31] * w288;
            v = lrelu(v);
            unsigned short h, l; cvt_duo(v, h, l);
            h1h_lds[row * 136 + colg] = h;
            h1l_lds[row * 136 + colg] = l;
        }
    }
    __syncthreads();

    // ---------- GEMM2 (MFMA bf16x3): (16 x 128) @ (128 x 256) + relu + sdot ----------
    {
        const unsigned short* h1rh = h1h_lds + lr * 136 + 4 * lg;
        const unsigned short* h1rl = h1l_lds + lr * 136 + 4 * lg;
        const int col0 = wv * 16 + lr;
        float bb0 = b2[col0], bb1 = b2[128 + col0];
        v4f acc0 = {bb0, bb0, bb0, bb0};
        v4f acc1 = {bb1, bb1, bb1, bb1};
        v8s Ah = {0,0,0,0,0,0,0,0}, Al = {0,0,0,0,0,0,0,0};
#pragma unroll
        for (int s = 0; s < 8; ++s) {             // s = ks*2 + ch
            float4* w4 = (float4*)wbuf[s & 1];
            w4[tid] = ta; w4[tid + 512] = tb;
            if (s < 7) { ta = gpk2[(s + 1) * 1024 + tid]; tb = gpk2[(s + 1) * 1024 + 512 + tid]; }
            __syncthreads();
            const unsigned short* wb = (const unsigned short*)wbuf[s & 1];
            if ((s & 1) == 0) {
                int k0 = (s >> 1) * 32;
                Ah = pack8(*(const v4s*)(h1rh + k0), *(const v4s*)(h1rh + k0 + 16));
                Al = pack8(*(const v4s*)(h1rl + k0), *(const v4s*)(h1rl + k0 + 16));
            }
            v8s Bh = *(const v8s*)(wb + wv * 512 + lane * 8);
            v8s Bl = *(const v8s*)(wb + 4096 + wv * 512 + lane * 8);
            if ((s & 1) == 0) {
                acc0 = MFMA(Ah, Bh, acc0, 0, 0, 0);
                acc0 = MFMA(Ah, Bl, acc0, 0, 0, 0);
                acc0 = MFMA(Al, Bh, acc0, 0, 0, 0);
            } else {
                acc1 = MFMA(Ah, Bh, acc1, 0, 0, 0);
                acc1 = MFMA(Ah, Bl, acc1, 0, 0, 0);
                acc1 = MFMA(Al, Bh, acc1, 0, 0, 0);
            }
        }
        float pr[4] = {0.f, 0.f, 0.f, 0.f};
#pragma unroll
        for (int r = 0; r < 4; ++r) {
            int row = lg * 4 + r;
            float v = acc0[r];
            if (apply_relu) v = fmaxf(v, 0.f);
            nexth[(node0 + row) * HD + col0] = v;
            pr[r] += v * av[64 + col0];
            float v2 = acc1[r];
            if (apply_relu) v2 = fmaxf(v2, 0.f);
            nexth[(node0 + row) * HD + 128 + col0] = v2;
            pr[r] += v2 * av[192 + col0];
        }
#pragma unroll
        for (int off = 1; off < 16; off <<= 1) {
#pragma unroll
            for (int r = 0; r < 4; ++r) pr[r] += __shfl_xor(pr[r], off);
        }
        if (lr == 0) {
#pragma unroll
            for (int r = 0; r < 4; ++r) red_lds[lg * 4 + r][wv] = pr[r];
        }
        __syncthreads();
        if (tid < TN) {
            float s = 0.f;
#pragma unroll
            for (int w = 0; w < 8; w++) s += red_lds[tid][w];
            sdot_next[node0 + tid] = s;
        }
    }
}

// ---------------- final kernel: 512 threads; glob mlp + concat + out mlp (fused, MFMA) ----------------
__global__ __launch_bounds__(512, 4) void final_kernel(
    const float* __restrict__ prevh, const float* __restrict__ pofeat,
    const float* __restrict__ gl_w1, const float* __restrict__ gl_b1,
    const float* __restrict__ gl_b2,
    const float* __restrict__ o_b1,
    const float* __restrict__ o_w2, const float* __restrict__ o_b2,
    float* __restrict__ out)
{
    __shared__ unsigned short x2h[16 * 520];
    __shared__ unsigned short x2l[16 * 520];
    __shared__ unsigned short g1h[16 * 136];
    __shared__ unsigned short g1l[16 * 136];
    __shared__ float wbuf[2][4096];
    __shared__ float ow2_lds[256];
    __shared__ float red_lds[16][8];

    const int tid = threadIdx.x;
    const int node0 = blockIdx.x * TN;
    const float4* gpkG = (const float4*)(g_wpk + 278528);
    const float4* gpkO = (const float4*)(g_wpk + 344064);
    float4 ta = gpkG[tid], tb = gpkG[512 + tid];

    for (int q = tid; q < TN * 64; q += 512) {
        int i = q >> 6, c4 = (q & 63) * 4;
        float4 v = *(const float4*)&prevh[(node0 + i) * HD + c4];
        unsigned short h, l;
        cvt_duo(v.x, h, l); x2h[i * 520 + c4 + 0] = h; x2l[i * 520 + c4 + 0] = l;
        cvt_duo(v.y, h, l); x2h[i * 520 + c4 + 1] = h; x2l[i * 520 + c4 + 1] = l;
        cvt_duo(v.z, h, l); x2h[i * 520 + c4 + 2] = h; x2l[i * 520 + c4 + 2] = l;
        cvt_duo(v.w, h, l); x2h[i * 520 + c4 + 3] = h; x2l[i * 520 + c4 + 3] = l;
    }
    for (int t = tid; t < TN * 128; t += 512) {
        int i = t >> 7, jj = t & 127;
        float v = lrelu(pofeat[node0 + i] * gl_w1[jj] + gl_b1[jj]);
        unsigned short h, l; cvt_duo(v, h, l);
        g1h[i * 136 + jj] = h; g1l[i * 136 + jj] = l;
    }
    if (tid < 256) ow2_lds[tid] = o_w2[tid];
    __syncthreads();

    const int lane = tid & 63, wv = tid >> 6;
    const int lr = lane & 15, lg = lane >> 4;
    const int col0 = wv * 16 + lr;

    // glob layer 2 (MFMA): (16x128)@(128x256) -> x2 duo cols 256..511
    {
        const unsigned short* grh = g1h + lr * 136 + 4 * lg;
        const unsigned short* grl = g1l + lr * 136 + 4 * lg;
        float bb0 = gl_b2[col0], bb1 = gl_b2[128 + col0];
        v4f acc0 = {bb0, bb0, bb0, bb0};
        v4f acc1 = {bb1, bb1, bb1, bb1};
        v8s Ah = {0,0,0,0,0,0,0,0}, Al = {0,0,0,0,0,0,0,0};
#pragma unroll
        for (int s = 0; s < 8; ++s) {
            float4* w4 = (float4*)wbuf[s & 1];
            w4[tid] = ta; w4[tid + 512] = tb;
            if (s < 7) { ta = gpkG[(s + 1) * 1024 + tid]; tb = gpkG[(s + 1) * 1024 + 512 + tid]; }
            else       { ta = gpkO[tid]; tb = gpkO[512 + tid]; }   // prefetch out1 stage 0
            __syncthreads();
            const unsigned short* wb = (const unsigned short*)wbuf[s & 1];
            if ((s & 1) == 0) {
                int k0 = (s >> 1) * 32;
                Ah = pack8(*(const v4s*)(grh + k0), *(const v4s*)(grh + k0 + 16));
                Al = pack8(*(const v4s*)(grl + k0), *(const v4s*)(grl + k0 + 16));
            }
            v8s Bh = *(const v8s*)(wb + wv * 512 + lane * 8);
            v8s Bl = *(const v8s*)(wb + 4096 + wv * 512 + lane * 8);
            if ((s & 1) == 0) {
                acc0 = MFMA(Ah, Bh, acc0, 0, 0, 0);
                acc0 = MFMA(Ah, Bl, acc0, 0, 0, 0);
                acc0 = MFMA(Al, Bh, acc0, 0, 0, 0);
            } else {
                acc1 = MFMA(Ah, Bh, acc1, 0, 0, 0);
                acc1 = MFMA(Ah, Bl, acc1, 0, 0, 0);
                acc1 = MFMA(Al, Bh, acc1, 0, 0, 0);
            }
        }
#pragma unroll
        for (int r = 0; r < 4; ++r) {
            int row = lg * 4 + r;
            unsigned short h, l;
            cvt_duo(acc0[r], h, l); x2h[row * 520 + 256 + col0] = h; x2l[row * 520 + 256 + col0] = l;
            cvt_duo(acc1[r], h, l); x2h[row * 520 + 384 + col0] = h; x2l[row * 520 + 384 + col0] = l;
        }
    }
    __syncthreads();

    // out layer 1 (MFMA, K=512, 32 stages) fused with out layer 2
    {
        const unsigned short* xrh = x2h + lr * 520 + 4 * lg;
        const unsigned short* xrl = x2l + lr * 520 + 4 * lg;
        float bb0 = o_b1[col0], bb1 = o_b1[128 + col0];
        v4f acc0 = {bb0, bb0, bb0, bb0};
        v4f acc1 = {bb1, bb1, bb1, bb1};
        v8s Ah = {0,0,0,0,0,0,0,0}, Al = {0,0,0,0,0,0,0,0};
        for (int s = 0; s < 32; ++s) {
            float4* w4 = (float4*)wbuf[s & 1];
            w4[tid] = ta; w4[tid + 512] = tb;
            if (s < 31) { ta = gpkO[(s + 1) * 1024 + tid]; tb = gpkO[(s + 1) * 1024 + 512 + tid]; }
            __syncthreads();
            const unsigned short* wb = (const unsigned short*)wbuf[s & 1];
            if ((s & 1) == 0) {
                int k0 = (s >> 1) * 32;
                Ah = pack8(*(const v4s*)(xrh + k0), *(const v4s*)(xrh + k0 + 16));
                Al = pack8(*(const v4s*)(xrl + k0), *(const v4s*)(xrl + k0 + 16));
            }
            v8s Bh = *(const v8s*)(wb + wv * 512 + lane * 8);
            v8s Bl = *(const v8s*)(wb + 4096 + wv * 512 + lane * 8);
            if ((s & 1) == 0) {
                acc0 = MFMA(Ah, Bh, acc0, 0, 0, 0);
                acc0 = MFMA(Ah, Bl, acc0, 0, 0, 0);
                acc0 = MFMA(Al, Bh, acc0, 0, 0, 0);
            } else {
                acc1 = MFMA(Ah, Bh, acc1, 0, 0, 0);
                acc1 = MFMA(Ah, Bl, acc1, 0, 0, 0);
                acc1 = MFMA(Al, Bh, acc1, 0, 0, 0);
            }
        }
        float pr[4] = {0.f, 0.f, 0.f, 0.f};
#pragma unroll
        for (int r = 0; r < 4; ++r) {
            pr[r] += lrelu(acc0[r]) * ow2_lds[col0];
            pr[r] += lrelu(acc1[r]) * ow2_lds[128 + col0];
        }
#pragma unroll
        for (int off = 1; off < 16; off <<= 1) {
#pragma unroll
            for (int r = 0; r < 4; ++r) pr[r] += __shfl_xor(pr[r], off);
        }
        if (lr == 0) {
#pragma unroll
            for (int r = 0; r < 4; ++r) red_lds[lg * 4 + r][wv] = pr[r];
        }
        __syncthreads();
        if (tid < TN) {
            float s = 0.f;
#pragma unroll
            for (int w = 0; w < 8; w++) s += red_lds[tid][w];
            out[node0 + tid] = s + o_b2[0];
        }
    }
}

extern "C" void kernel_launch(void* const* d_in, const int* in_sizes, int n_in,
                              void* d_out, int out_size, void* d_ws, size_t ws_size,
                              hipStream_t stream)
{
    const float* delay    = (const float*)d_in[0];
    const float* feat     = (const float*)d_in[1];
    const float* bitpos   = (const float*)d_in[2];
    const float* pofeat   = (const float*)d_in[3];
    const int*   srcidx   = (const int*)  d_in[4];
    const float* pi_w1    = (const float*)d_in[5];
    const float* pi_b1    = (const float*)d_in[6];
    const float* pi_w2    = (const float*)d_in[7];
    const float* pi_b2    = (const float*)d_in[8];
    const float* gate_w1  = (const float*)d_in[9];
    const float* gate_b1  = (const float*)d_in[10];
    const float* gate_w2  = (const float*)d_in[11];
    const float* gate_b2  = (const float*)d_in[12];
    const float* mod_w1   = (const float*)d_in[13];
    const float* mod_b1   = (const float*)d_in[14];
    const float* mod_w2   = (const float*)d_in[15];
    const float* mod_b2   = (const float*)d_in[16];
    const float* type_w1  = (const float*)d_in[17];
    const float* type_b1  = (const float*)d_in[18];
    const float* type_w2  = (const float*)d_in[19];
    const float* type_b2  = (const float*)d_in[20];
    const float* pos_w1   = (const float*)d_in[21];
    const float* pos_b1   = (const float*)d_in[22];
    const float* pos_w2   = (const float*)d_in[23];
    const float* pos_b2   = (const float*)d_in[24];
    const float* attn_vec = (const float*)d_in[25];
    const float* glob_w1  = (const float*)d_in[26];
    const float* glob_b1  = (const float*)d_in[27];
    const float* glob_w2  = (const float*)d_in[28];
    const float* glob_b2  = (const float*)d_in[29];
    const float* out_w1   = (const float*)d_in[30];
    const float* out_b1   = (const float*)d_in[31];
    const float* out_w2   = (const float*)d_in[32];
    const float* out_b2   = (const float*)d_in[33];

    float* buf0 = (float*)d_ws;
    float* buf1 = buf0 + (size_t)NP * HD;
    float* sd0  = buf1 + (size_t)NP * HD;
    float* sd1  = sd0 + NP;

    prep_kernel<<<1184, 256, 0, stream>>>(gate_w1, mod_w1, gate_w2, mod_w2, glob_w2, out_w1);

    pi_kernel<<<NP / TN, 256, 0, stream>>>(delay, pi_w1, pi_b1, pi_w2, pi_b2,
                                           attn_vec, buf0, sd0);

    for (int l = 0; l < NLVL; l++) {
        float* pv = (l & 1) ? buf1 : buf0;
        float* nx = (l & 1) ? buf0 : buf1;
        float* sp = (l & 1) ? sd1 : sd0;
        float* sn = (l & 1) ? sd0 : sd1;
        level_kernel<<<NP / TN, 512, 0, stream>>>(
            pv, nx, sp, sn, feat, bitpos, srcidx,
            gate_w1, gate_b1, gate_b2,
            mod_w1, mod_b1, mod_b2,
            type_w1, type_b1, type_w2, type_b2,
            pos_w1, pos_b1, pos_w2, pos_b2,
            attn_vec, l, (l != NLVL - 1) ? 1 : 0);
    }

    final_kernel<<<NP / TN, 512, 0, stream>>>(
        buf1, pofeat,
        glob_w1, glob_b1, glob_b2,
        out_b1, out_w2, out_b2,
        (float*)d_out);
}

// Round 14
// 313.632 us; speedup vs baseline: 2.1126x; 1.1070x over previous
//
#include <hip/hip_runtime.h>
#include <math.h>

#define HD   256
#define FIN  32
#define NP   8192
#define PGH  4096
#define NLVL 15
#define TN   16

typedef __attribute__((ext_vector_type(4))) short v4s;
typedef __attribute__((ext_vector_type(8))) short v8s;
typedef __attribute__((ext_vector_type(4))) float v4f;

#define MFMA __builtin_amdgcn_mfma_f32_16x16x32_bf16

// packed bf16 hi/lo fragment-layout weights (written by prep_kernel each launch)
// bases (ushorts): g_w1 0 (73728), m_w1 73728, g_w2 147456, m_w2 212992, gl_w2 278528, o_w1 344064 (262144)
__device__ __align__(16) unsigned short g_wpk[606208];

__device__ __forceinline__ float lrelu(float x) { return x > 0.f ? x : 0.1f * x; }

__device__ __forceinline__ void cvt_duo(float v, unsigned short& hi, unsigned short& lo) {
    unsigned int u = __float_as_uint(v);
    unsigned int r = u + 0x7fffu + ((u >> 16) & 1u);       // RNE to bf16
    hi = (unsigned short)(r >> 16);
    float d = v - __uint_as_float((unsigned int)hi << 16);
    unsigned int u2 = __float_as_uint(d);
    unsigned int r2 = u2 + 0x7fffu + ((u2 >> 16) & 1u);
    lo = (unsigned short)(r2 >> 16);
}

__device__ __forceinline__ v8s pack8(v4s a, v4s b) {
    v8s r; r[0]=a[0]; r[1]=a[1]; r[2]=a[2]; r[3]=a[3]; r[4]=b[0]; r[5]=b[1]; r[6]=b[2]; r[7]=b[3];
    return r;
}

// ---------------- prep: pack weights to bf16 hi/lo MFMA-fragment layout ----------------
__global__ __launch_bounds__(256) void prep_kernel(
    const float* __restrict__ gw1, const float* __restrict__ mw1,
    const float* __restrict__ gw2, const float* __restrict__ mw2,
    const float* __restrict__ glw2, const float* __restrict__ ow1)
{
    int t = blockIdx.x * 256 + threadIdx.x;
    const float* src; int base, N, idx;
    if (t < 36864)       { src = gw1;  base = 0;      N = 128; idx = t; }
    else if (t < 73728)  { src = mw1;  base = 73728;  N = 128; idx = t - 36864; }
    else if (t < 106496) { src = gw2;  base = 147456; N = 256; idx = t - 73728; }
    else if (t < 139264) { src = mw2;  base = 212992; N = 256; idx = t - 106496; }
    else if (t < 172032) { src = glw2; base = 278528; N = 256; idx = t - 139264; }
    else if (t < 303104) { src = ow1;  base = 344064; N = 256; idx = t - 172032; }
    else return;
    int sh = (N == 128) ? 7 : 8;
    int k = idx >> sh, col = idx & (N - 1);
    float v = src[idx];
    unsigned short hi, lo; cvt_duo(v, hi, lo);
    int ks = k >> 5, kk = k & 31;
    int ch = col >> 7, cc = col & 127, ct = cc >> 4;
    int nch = N >> 7;
    int l = ((kk & 15) >> 2) * 16 + (cc & 15);
    int w = (kk & 3) + (kk >> 4) * 4;
    int off = ((ks * nch + ch) * 2) * 4096 + ct * 512 + l * 8 + w;
    g_wpk[base + off] = hi;
    g_wpk[base + off + 4096] = lo;
}

// ---------------- pi kernel: prev_h = mlp(delay), + sdot epilogue (fp32) ----------------
__global__ __launch_bounds__(256) void pi_kernel(
    const float* __restrict__ delay,
    const float* __restrict__ w1, const float* __restrict__ b1,
    const float* __restrict__ w2, const float* __restrict__ b2,
    const float* __restrict__ av,
    float* __restrict__ outh, float* __restrict__ sdot)
{
    __shared__ float g1[TN][132];
    const int tid = threadIdx.x;
    const int node0 = blockIdx.x * TN;

    for (int t = tid; t < TN * 128; t += 256) {
        int i = t >> 7, jj = t & 127;
        g1[i][jj] = lrelu(delay[node0 + i] * w1[jj] + b1[jj]);
    }
    __syncthreads();

    const int j = (tid & 63) * 4;
    const int rg = (tid >> 6) * 4;
    float acc[4][4];
    float4 bv = *(const float4*)&b2[j];
#pragma unroll
    for (int ri = 0; ri < 4; ri++) { acc[ri][0] = bv.x; acc[ri][1] = bv.y; acc[ri][2] = bv.z; acc[ri][3] = bv.w; }

#pragma unroll 2
    for (int k = 0; k < 128; k += 4) {
        float4 x0 = *(const float4*)&g1[rg + 0][k];
        float4 x1 = *(const float4*)&g1[rg + 1][k];
        float4 x2v = *(const float4*)&g1[rg + 2][k];
        float4 x3 = *(const float4*)&g1[rg + 3][k];
        const float* wp = w2 + (size_t)k * 256 + j;
#define PIK(comp, off) { float4 wv = *(const float4*)(wp + (off) * 256); \
    acc[0][0] += x0.comp * wv.x; acc[0][1] += x0.comp * wv.y; acc[0][2] += x0.comp * wv.z; acc[0][3] += x0.comp * wv.w; \
    acc[1][0] += x1.comp * wv.x; acc[1][1] += x1.comp * wv.y; acc[1][2] += x1.comp * wv.z; acc[1][3] += x1.comp * wv.w; \
    acc[2][0] += x2v.comp * wv.x; acc[2][1] += x2v.comp * wv.y; acc[2][2] += x2v.comp * wv.z; acc[2][3] += x2v.comp * wv.w; \
    acc[3][0] += x3.comp * wv.x; acc[3][1] += x3.comp * wv.y; acc[3][2] += x3.comp * wv.z; acc[3][3] += x3.comp * wv.w; }
        PIK(x, 0) PIK(y, 1) PIK(z, 2) PIK(w, 3)
#undef PIK
    }
    float4 avj = *(const float4*)&av[64 + j];
#pragma unroll
    for (int ri = 0; ri < 4; ri++) {
        *(float4*)&outh[(node0 + rg + ri) * HD + j] =
            make_float4(acc[ri][0], acc[ri][1], acc[ri][2], acc[ri][3]);
        float p = acc[ri][0] * avj.x + acc[ri][1] * avj.y + acc[ri][2] * avj.z + acc[ri][3] * avj.w;
#pragma unroll
        for (int off = 1; off < 64; off <<= 1) p += __shfl_xor(p, off);
        if ((tid & 63) == 0) sdot[node0 + rg + ri] = p;
    }
}

// ---------------- per-level kernel: 512 threads; blocks 0..255 gate, 256..511 mod ----------------
__global__ __launch_bounds__(512, 4) void level_kernel(
    const float* __restrict__ prevh, float* __restrict__ nexth,
    const float* __restrict__ sdot_prev, float* __restrict__ sdot_next,
    const float* __restrict__ feat, const float* __restrict__ bitpos,
    const int* __restrict__ srcidx,
    const float* __restrict__ g_w1, const float* __restrict__ g_b1,
    const float* __restrict__ g_b2,
    const float* __restrict__ m_w1, const float* __restrict__ m_b1,
    const float* __restrict__ m_b2,
    const float* __restrict__ t_w1, const float* __restrict__ t_b1,
    const float* __restrict__ t_w2, const float* __restrict__ t_b2,
    const float* __restrict__ p_w1, const float* __restrict__ p_b1,
    const float* __restrict__ p_w2, const float* __restrict__ p_b2,
    const float* __restrict__ av,
    int level, int apply_relu)
{
    __shared__ unsigned short xh_lds[16 * 296];
    __shared__ unsigned short xl_lds[16 * 296];
    __shared__ unsigned short h1h_lds[16 * 136];
    __shared__ unsigned short h1l_lds[16 * 136];
    __shared__ int   src_lds[128];
    __shared__ float bp_lds[128];
    __shared__ float dstf_lds[16][32];
    __shared__ float ztt_lds[16][32];
    __shared__ float alpha_lds[128];
    __shared__ float xbp_lds[16];
    __shared__ float av_lds[64];
    __shared__ float tw2av_lds[32];
    __shared__ float pw2av_lds[32];
    __shared__ float bias_av[2];
    __shared__ float red_lds[16][8];

    const int tid = threadIdx.x;
    const bool is_gate = (blockIdx.x < 256);
    const int node0 = is_gate ? (blockIdx.x * TN) : (PGH + ((int)blockIdx.x - 256) * TN);

    const float* w1 = is_gate ? g_w1 : m_w1;
    const float* b1 = is_gate ? g_b1 : m_b1;
    const float* b2 = is_gate ? g_b2 : m_b2;
    const unsigned short* pk1 = g_wpk + (is_gate ? 0 : 73728);
    const unsigned short* pk2 = g_wpk + (is_gate ? 147456 : 212992);

    if (tid < 128) src_lds[tid] = srcidx[(level * NP + node0) * 8 + tid];

    if (is_gate) {
        {
            int i = tid >> 5, k = tid & 31;
            float v = feat[((level + 1) * NP + node0 + i) * FIN + k];
            unsigned short h, l; cvt_duo(v, h, l);
            xh_lds[i * 296 + 256 + k] = h; xl_lds[i * 296 + 256 + k] = l;
        }
        __syncthreads();
        // gather + per-channel softmax: thread = (half, channel), 4-node chunks
        {
            const int c = tid & 255, sh = (tid >> 8) * 8;
            for (int s0 = 0; s0 < 8; s0 += 4) {
                const int* spA = &src_lds[(sh + s0 + 0) * 8];
                const int* spB = &src_lds[(sh + s0 + 1) * 8];
                const int* spC = &src_lds[(sh + s0 + 2) * 8];
                const int* spD = &src_lds[(sh + s0 + 3) * 8];
                float ma[8], mb[8], mc[8], md[8];
#pragma unroll
                for (int f = 0; f < 8; f++) ma[f] = prevh[spA[f] * HD + c];
#pragma unroll
                for (int f = 0; f < 8; f++) mb[f] = prevh[spB[f] * HD + c];
#pragma unroll
                for (int f = 0; f < 8; f++) mc[f] = prevh[spC[f] * HD + c];
#pragma unroll
                for (int f = 0; f < 8; f++) md[f] = prevh[spD[f] * HD + c];
                float mxa = -1e30f, mxb = -1e30f, mxc = -1e30f, mxd = -1e30f;
#pragma unroll
                for (int f = 0; f < 8; f++) {
                    mxa = fmaxf(mxa, ma[f]); mxb = fmaxf(mxb, mb[f]);
                    mxc = fmaxf(mxc, mc[f]); mxd = fmaxf(mxd, md[f]);
                }
                float sa = 0.f, wsa = 0.f, sb = 0.f, wsb = 0.f;
                float sc = 0.f, wsc = 0.f, sd = 0.f, wsd = 0.f;
#pragma unroll
                for (int f = 0; f < 8; f++) {
                    float ea = __expf(ma[f] - mxa); sa += ea; wsa += ma[f] * ea;
                    float eb = __expf(mb[f] - mxb); sb += eb; wsb += mb[f] * eb;
                    float ec = __expf(mc[f] - mxc); sc += ec; wsc += mc[f] * ec;
                    float ed = __expf(md[f] - mxd); sd += ed; wsd += md[f] * ed;
                }
                unsigned short h, l;
                cvt_duo(wsa / sa, h, l); xh_lds[(sh+s0+0)*296 + c] = h; xl_lds[(sh+s0+0)*296 + c] = l;
                cvt_duo(wsb / sb, h, l); xh_lds[(sh+s0+1)*296 + c] = h; xl_lds[(sh+s0+1)*296 + c] = l;
                cvt_duo(wsc / sc, h, l); xh_lds[(sh+s0+2)*296 + c] = h; xl_lds[(sh+s0+2)*296 + c] = l;
                cvt_duo(wsd / sd, h, l); xh_lds[(sh+s0+3)*296 + c] = h; xl_lds[(sh+s0+3)*296 + c] = l;
            }
        }
        __syncthreads();
    } else {
        if (tid < 128) bp_lds[tid] = bitpos[(level * NP + node0) * 8 + tid];
        {
            int i = tid >> 5, k = tid & 31;
            float v = feat[((level + 1) * NP + node0 + i) * FIN + k];
            dstf_lds[i][k] = v;
            unsigned short h, l; cvt_duo(v, h, l);
            xh_lds[i * 296 + 257 + k] = h; xl_lds[i * 296 + 257 + k] = l;
        }
        if (tid < 64) av_lds[tid] = av[tid];
        __syncthreads();

        // ztt = lrelu(dstf @ t_w1 + t_b1)
        {
            int i = tid >> 5, jj = tid & 31;
            float a = t_b1[jj];
#pragma unroll 8
            for (int k = 0; k < 32; k++) a += dstf_lds[i][k] * t_w1[k * 32 + jj];
            ztt_lds[i][jj] = lrelu(a);
        }
        // fold attn_vec through second MLP layers (exact linear reassociation)
        if (tid < 32) {
            float s = 0.f;
#pragma unroll 8
            for (int jj = 0; jj < 32; jj++) s += t_w2[tid * 32 + jj] * av_lds[jj];
            tw2av_lds[tid] = s;
        } else if (tid < 64) {
            int k = tid - 32;
            float s = 0.f;
#pragma unroll 8
            for (int jj = 0; jj < 32; jj++) s += p_w2[k * 32 + jj] * av_lds[32 + jj];
            pw2av_lds[k] = s;
        } else if (tid == 64) {
            float s = 0.f;
#pragma unroll 8
            for (int jj = 0; jj < 32; jj++) s += t_b2[jj] * av_lds[jj];
            bias_av[0] = s;
        } else if (tid == 65) {
            float s = 0.f;
#pragma unroll 8
            for (int jj = 0; jj < 32; jj++) s += p_b2[jj] * av_lds[32 + jj];
            bias_av[1] = s;
        }
        __syncthreads();

        // logits + softmax over fanin (hoisted sdot): first 256 threads, tid = i*16 + f*2 + jg
        if (tid < 256) {
            const int jg = tid & 1, f = (tid >> 1) & 7, i = tid >> 4;
            const float sv = sdot_prev[src_lds[i * 8 + f]];
            const float bpv = bp_lds[i * 8 + f];
            float part = 0.f;
            const int k0 = jg * 16;
#pragma unroll
            for (int k = k0; k < k0 + 16; k++) {
                float h1pk = lrelu(bpv * p_w1[k] + p_b1[k]);
                part += h1pk * pw2av_lds[k];
                part += ztt_lds[i][k] * tw2av_lds[k];
            }
            part += __shfl_xor(part, 1);
            float logit = part + bias_av[0] + bias_av[1] + sv;
            float mx = logit;
            mx = fmaxf(mx, __shfl_xor(mx, 2));
            mx = fmaxf(mx, __shfl_xor(mx, 4));
            mx = fmaxf(mx, __shfl_xor(mx, 8));
            float e = __expf(logit - mx);
            float ssum = e;
            ssum += __shfl_xor(ssum, 2);
            ssum += __shfl_xor(ssum, 4);
            ssum += __shfl_xor(ssum, 8);
            float alpha = e / ssum;
            if (jg == 0) alpha_lds[i * 8 + f] = alpha;
            float ab = alpha * bpv;
            ab += __shfl_xor(ab, 2);
            ab += __shfl_xor(ab, 4);
            ab += __shfl_xor(ab, 8);
            if ((tid & 15) == 0) xbp_lds[i] = ab;
        }
        __syncthreads();

        // neigh_m: thread = (half, channel), 4-node chunks; write x duo
        {
            const int c = tid & 255, sh = (tid >> 8) * 8;
            for (int s0 = 0; s0 < 8; s0 += 4) {
                const int* spA = &src_lds[(sh + s0 + 0) * 8];
                const int* spB = &src_lds[(sh + s0 + 1) * 8];
                const int* spC = &src_lds[(sh + s0 + 2) * 8];
                const int* spD = &src_lds[(sh + s0 + 3) * 8];
                float ma[8], mb[8], mc[8], md[8];
#pragma unroll
                for (int f = 0; f < 8; f++) ma[f] = prevh[spA[f] * HD + c];
#pragma unroll
                for (int f = 0; f < 8; f++) mb[f] = prevh[spB[f] * HD + c];
#pragma unroll
                for (int f = 0; f < 8; f++) mc[f] = prevh[spC[f] * HD + c];
#pragma unroll
                for (int f = 0; f < 8; f++) md[f] = prevh[spD[f] * HD + c];
                const float* apA = &alpha_lds[(sh + s0 + 0) * 8];
                const float* apB = &alpha_lds[(sh + s0 + 1) * 8];
                const float* apC = &alpha_lds[(sh + s0 + 2) * 8];
                const float* apD = &alpha_lds[(sh + s0 + 3) * 8];
                float aa = 0.f, ab2 = 0.f, ac = 0.f, ad = 0.f;
#pragma unroll
                for (int f = 0; f < 8; f++) {
                    aa  += apA[f] * ma[f]; ab2 += apB[f] * mb[f];
                    ac  += apC[f] * mc[f]; ad  += apD[f] * md[f];
                }
                unsigned short h, l;
                cvt_duo(aa,  h, l); xh_lds[(sh+s0+0)*296 + c] = h; xl_lds[(sh+s0+0)*296 + c] = l;
                cvt_duo(ab2, h, l); xh_lds[(sh+s0+1)*296 + c] = h; xl_lds[(sh+s0+1)*296 + c] = l;
                cvt_duo(ac,  h, l); xh_lds[(sh+s0+2)*296 + c] = h; xl_lds[(sh+s0+2)*296 + c] = l;
                cvt_duo(ad,  h, l); xh_lds[(sh+s0+3)*296 + c] = h; xl_lds[(sh+s0+3)*296 + c] = l;
            }
        }
        if (tid < TN) {
            unsigned short h, l; cvt_duo(xbp_lds[tid], h, l);
            xh_lds[tid * 296 + 256] = h; xl_lds[tid * 296 + 256] = l;
        }
        __syncthreads();
    }

    const int lane = tid & 63, wv = tid >> 6;
    const int lr = lane & 15, lg = lane >> 4;

    // ---------- GEMM1 (MFMA bf16x3): (16 x 288) @ (288 x 128); B direct from L2 ----------
    {
        const unsigned short* xrh = xh_lds + lr * 296 + 4 * lg;
        const unsigned short* xrl = xl_lds + lr * 296 + 4 * lg;
        const int colg = wv * 16 + lr;
        float bb = b1[colg];
        v4f acc = {bb, bb, bb, bb};
#pragma unroll
        for (int s = 0; s < 9; ++s) {
            const unsigned short* wb = pk1 + s * 8192 + wv * 512 + lane * 8;
            v8s Bh = *(const v8s*)(wb);
            v8s Bl = *(const v8s*)(wb + 4096);
            int k0 = s * 32;
            v8s Ah = pack8(*(const v4s*)(xrh + k0), *(const v4s*)(xrh + k0 + 16));
            v8s Al = pack8(*(const v4s*)(xrl + k0), *(const v4s*)(xrl + k0 + 16));
            acc = MFMA(Ah, Bh, acc, 0, 0, 0);
            acc = MFMA(Ah, Bl, acc, 0, 0, 0);
            acc = MFMA(Al, Bh, acc, 0, 0, 0);
        }
        float w288 = is_gate ? 0.f : w1[288 * 128 + colg];
#pragma unroll
        for (int r = 0; r < 4; ++r) {
            int row = lg * 4 + r;
            float v = acc[r];
            if (!is_gate) v += dstf_lds[row][31] * w288;
            v = lrelu(v);
            unsigned short h, l; cvt_duo(v, h, l);
            h1h_lds[row * 136 + colg] = h;
            h1l_lds[row * 136 + colg] = l;
        }
    }
    __syncthreads();

    // ---------- GEMM2 (MFMA bf16x3): (16 x 128) @ (128 x 256) + relu + sdot; B direct ----------
    {
        const unsigned short* h1rh = h1h_lds + lr * 136 + 4 * lg;
        const unsigned short* h1rl = h1l_lds + lr * 136 + 4 * lg;
        const int col0 = wv * 16 + lr;
        float bb0 = b2[col0], bb1 = b2[128 + col0];
        v4f acc0 = {bb0, bb0, bb0, bb0};
        v4f acc1 = {bb1, bb1, bb1, bb1};
#pragma unroll
        for (int ks = 0; ks < 4; ++ks) {
            int k0 = ks * 32;
            v8s Ah = pack8(*(const v4s*)(h1rh + k0), *(const v4s*)(h1rh + k0 + 16));
            v8s Al = pack8(*(const v4s*)(h1rl + k0), *(const v4s*)(h1rl + k0 + 16));
            const unsigned short* wb0 = pk2 + (ks * 2 + 0) * 8192 + wv * 512 + lane * 8;
            const unsigned short* wb1 = pk2 + (ks * 2 + 1) * 8192 + wv * 512 + lane * 8;
            v8s Bh0 = *(const v8s*)(wb0);
            v8s Bl0 = *(const v8s*)(wb0 + 4096);
            v8s Bh1 = *(const v8s*)(wb1);
            v8s Bl1 = *(const v8s*)(wb1 + 4096);
            acc0 = MFMA(Ah, Bh0, acc0, 0, 0, 0);
            acc0 = MFMA(Ah, Bl0, acc0, 0, 0, 0);
            acc0 = MFMA(Al, Bh0, acc0, 0, 0, 0);
            acc1 = MFMA(Ah, Bh1, acc1, 0, 0, 0);
            acc1 = MFMA(Ah, Bl1, acc1, 0, 0, 0);
            acc1 = MFMA(Al, Bh1, acc1, 0, 0, 0);
        }
        float pr[4] = {0.f, 0.f, 0.f, 0.f};
#pragma unroll
        for (int r = 0; r < 4; ++r) {
            int row = lg * 4 + r;
            float v = acc0[r];
            if (apply_relu) v = fmaxf(v, 0.f);
            nexth[(node0 + row) * HD + col0] = v;
            pr[r] += v * av[64 + col0];
            float v2 = acc1[r];
            if (apply_relu) v2 = fmaxf(v2, 0.f);
            nexth[(node0 + row) * HD + 128 + col0] = v2;
            pr[r] += v2 * av[192 + col0];
        }
#pragma unroll
        for (int off = 1; off < 16; off <<= 1) {
#pragma unroll
            for (int r = 0; r < 4; ++r) pr[r] += __shfl_xor(pr[r], off);
        }
        if (lr == 0) {
#pragma unroll
            for (int r = 0; r < 4; ++r) red_lds[lg * 4 + r][wv] = pr[r];
        }
        __syncthreads();
        if (tid < TN) {
            float s = 0.f;
#pragma unroll
            for (int w = 0; w < 8; w++) s += red_lds[tid][w];
            sdot_next[node0 + tid] = s;
        }
    }
}

// ---------------- final kernel: 512 threads; glob mlp + concat + out mlp (fused, MFMA) ----------------
__global__ __launch_bounds__(512, 4) void final_kernel(
    const float* __restrict__ prevh, const float* __restrict__ pofeat,
    const float* __restrict__ gl_w1, const float* __restrict__ gl_b1,
    const float* __restrict__ gl_b2,
    const float* __restrict__ o_b1,
    const float* __restrict__ o_w2, const float* __restrict__ o_b2,
    float* __restrict__ out)
{
    __shared__ unsigned short x2h[16 * 520];
    __shared__ unsigned short x2l[16 * 520];
    __shared__ unsigned short g1h[16 * 136];
    __shared__ unsigned short g1l[16 * 136];
    __shared__ float ow2_lds[256];
    __shared__ float red_lds[16][8];

    const int tid = threadIdx.x;
    const int node0 = blockIdx.x * TN;
    const unsigned short* pkG = g_wpk + 278528;
    const unsigned short* pkO = g_wpk + 344064;

    for (int q = tid; q < TN * 64; q += 512) {
        int i = q >> 6, c4 = (q & 63) * 4;
        float4 v = *(const float4*)&prevh[(node0 + i) * HD + c4];
        unsigned short h, l;
        cvt_duo(v.x, h, l); x2h[i * 520 + c4 + 0] = h; x2l[i * 520 + c4 + 0] = l;
        cvt_duo(v.y, h, l); x2h[i * 520 + c4 + 1] = h; x2l[i * 520 + c4 + 1] = l;
        cvt_duo(v.z, h, l); x2h[i * 520 + c4 + 2] = h; x2l[i * 520 + c4 + 2] = l;
        cvt_duo(v.w, h, l); x2h[i * 520 + c4 + 3] = h; x2l[i * 520 + c4 + 3] = l;
    }
    for (int t = tid; t < TN * 128; t += 512) {
        int i = t >> 7, jj = t & 127;
        float v = lrelu(pofeat[node0 + i] * gl_w1[jj] + gl_b1[jj]);
        unsigned short h, l; cvt_duo(v, h, l);
        g1h[i * 136 + jj] = h; g1l[i * 136 + jj] = l;
    }
    if (tid < 256) ow2_lds[tid] = o_w2[tid];
    __syncthreads();

    const int lane = tid & 63, wv = tid >> 6;
    const int lr = lane & 15, lg = lane >> 4;
    const int col0 = wv * 16 + lr;

    // glob layer 2 (MFMA): (16x128)@(128x256) -> x2 duo cols 256..511; B direct
    {
        const unsigned short* grh = g1h + lr * 136 + 4 * lg;
        const unsigned short* grl = g1l + lr * 136 + 4 * lg;
        float bb0 = gl_b2[col0], bb1 = gl_b2[128 + col0];
        v4f acc0 = {bb0, bb0, bb0, bb0};
        v4f acc1 = {bb1, bb1, bb1, bb1};
#pragma unroll
        for (int ks = 0; ks < 4; ++ks) {
            int k0 = ks * 32;
            v8s Ah = pack8(*(const v4s*)(grh + k0), *(const v4s*)(grh + k0 + 16));
            v8s Al = pack8(*(const v4s*)(grl + k0), *(const v4s*)(grl + k0 + 16));
            const unsigned short* wb0 = pkG + (ks * 2 + 0) * 8192 + wv * 512 + lane * 8;
            const unsigned short* wb1 = pkG + (ks * 2 + 1) * 8192 + wv * 512 + lane * 8;
            v8s Bh0 = *(const v8s*)(wb0);
            v8s Bl0 = *(const v8s*)(wb0 + 4096);
            v8s Bh1 = *(const v8s*)(wb1);
            v8s Bl1 = *(const v8s*)(wb1 + 4096);
            acc0 = MFMA(Ah, Bh0, acc0, 0, 0, 0);
            acc0 = MFMA(Ah, Bl0, acc0, 0, 0, 0);
            acc0 = MFMA(Al, Bh0, acc0, 0, 0, 0);
            acc1 = MFMA(Ah, Bh1, acc1, 0, 0, 0);
            acc1 = MFMA(Ah, Bl1, acc1, 0, 0, 0);
            acc1 = MFMA(Al, Bh1, acc1, 0, 0, 0);
        }
#pragma unroll
        for (int r = 0; r < 4; ++r) {
            int row = lg * 4 + r;
            unsigned short h, l;
            cvt_duo(acc0[r], h, l); x2h[row * 520 + 256 + col0] = h; x2l[row * 520 + 256 + col0] = l;
            cvt_duo(acc1[r], h, l); x2h[row * 520 + 384 + col0] = h; x2l[row * 520 + 384 + col0] = l;
        }
    }
    __syncthreads();

    // out layer 1 (MFMA, K=512, 16 K-stages x 2 col-chunks) fused with out layer 2; B direct
    {
        const unsigned short* xrh = x2h + lr * 520 + 4 * lg;
        const unsigned short* xrl = x2l + lr * 520 + 4 * lg;
        float bb0 = o_b1[col0], bb1 = o_b1[128 + col0];
        v4f acc0 = {bb0, bb0, bb0, bb0};
        v4f acc1 = {bb1, bb1, bb1, bb1};
        for (int ks = 0; ks < 16; ++ks) {
            int k0 = ks * 32;
            v8s Ah = pack8(*(const v4s*)(xrh + k0), *(const v4s*)(xrh + k0 + 16));
            v8s Al = pack8(*(const v4s*)(xrl + k0), *(const v4s*)(xrl + k0 + 16));
            const unsigned short* wb0 = pkO + (ks * 2 + 0) * 8192 + wv * 512 + lane * 8;
            const unsigned short* wb1 = pkO + (ks * 2 + 1) * 8192 + wv * 512 + lane * 8;
            v8s Bh0 = *(const v8s*)(wb0);
            v8s Bl0 = *(const v8s*)(wb0 + 4096);
            v8s Bh1 = *(const v8s*)(wb1);
            v8s Bl1 = *(const v8s*)(wb1 + 4096);
            acc0 = MFMA(Ah, Bh0, acc0, 0, 0, 0);
            acc0 = MFMA(Ah, Bl0, acc0, 0, 0, 0);
            acc0 = MFMA(Al, Bh0, acc0, 0, 0, 0);
            acc1 = MFMA(Ah, Bh1, acc1, 0, 0, 0);
            acc1 = MFMA(Ah, Bl1, acc1, 0, 0, 0);
            acc1 = MFMA(Al, Bh1, acc1, 0, 0, 0);
        }
        float pr[4] = {0.f, 0.f, 0.f, 0.f};
#pragma unroll
        for (int r = 0; r < 4; ++r) {
            pr[r] += lrelu(acc0[r]) * ow2_lds[col0];
            pr[r] += lrelu(acc1[r]) * ow2_lds[128 + col0];
        }
#pragma unroll
        for (int off = 1; off < 16; off <<= 1) {
#pragma unroll
            for (int r = 0; r < 4; ++r) pr[r] += __shfl_xor(pr[r], off);
        }
        if (lr == 0) {
#pragma unroll
            for (int r = 0; r < 4; ++r) red_lds[lg * 4 + r][wv] = pr[r];
        }
        __syncthreads();
        if (tid < TN) {
            float s = 0.f;
#pragma unroll
            for (int w = 0; w < 8; w++) s += red_lds[tid][w];
            out[node0 + tid] = s + o_b2[0];
        }
    }
}

extern "C" void kernel_launch(void* const* d_in, const int* in_sizes, int n_in,
                              void* d_out, int out_size, void* d_ws, size_t ws_size,
                              hipStream_t stream)
{
    const float* delay    = (const float*)d_in[0];
    const float* feat     = (const float*)d_in[1];
    const float* bitpos   = (const float*)d_in[2];
    const float* pofeat   = (const float*)d_in[3];
    const int*   srcidx   = (const int*)  d_in[4];
    const float* pi_w1    = (const float*)d_in[5];
    const float* pi_b1    = (const float*)d_in[6];
    const float* pi_w2    = (const float*)d_in[7];
    const float* pi_b2    = (const float*)d_in[8];
    const float* gate_w1  = (const float*)d_in[9];
    const float* gate_b1  = (const float*)d_in[10];
    const float* gate_w2  = (const float*)d_in[11];
    const float* gate_b2  = (const float*)d_in[12];
    const float* mod_w1   = (const float*)d_in[13];
    const float* mod_b1   = (const float*)d_in[14];
    const float* mod_w2   = (const float*)d_in[15];
    const float* mod_b2   = (const float*)d_in[16];
    const float* type_w1  = (const float*)d_in[17];
    const float* type_b1  = (const float*)d_in[18];
    const float* type_w2  = (const float*)d_in[19];
    const float* type_b2  = (const float*)d_in[20];
    const float* pos_w1   = (const float*)d_in[21];
    const float* pos_b1   = (const float*)d_in[22];
    const float* pos_w2   = (const float*)d_in[23];
    const float* pos_b2   = (const float*)d_in[24];
    const float* attn_vec = (const float*)d_in[25];
    const float* glob_w1  = (const float*)d_in[26];
    const float* glob_b1  = (const float*)d_in[27];
    const float* glob_w2  = (const float*)d_in[28];
    const float* glob_b2  = (const float*)d_in[29];
    const float* out_w1   = (const float*)d_in[30];
    const float* out_b1   = (const float*)d_in[31];
    const float* out_w2   = (const float*)d_in[32];
    const float* out_b2   = (const float*)d_in[33];

    float* buf0 = (float*)d_ws;
    float* buf1 = buf0 + (size_t)NP * HD;
    float* sd0  = buf1 + (size_t)NP * HD;
    float* sd1  = sd0 + NP;

    prep_kernel<<<1184, 256, 0, stream>>>(gate_w1, mod_w1, gate_w2, mod_w2, glob_w2, out_w1);

    pi_kernel<<<NP / TN, 256, 0, stream>>>(delay, pi_w1, pi_b1, pi_w2, pi_b2,
                                           attn_vec, buf0, sd0);

    for (int l = 0; l < NLVL; l++) {
        float* pv = (l & 1) ? buf1 : buf0;
        float* nx = (l & 1) ? buf0 : buf1;
        float* sp = (l & 1) ? sd1 : sd0;
        float* sn = (l & 1) ? sd0 : sd1;
        level_kernel<<<NP / TN, 512, 0, stream>>>(
            pv, nx, sp, sn, feat, bitpos, srcidx,
            gate_w1, gate_b1, gate_b2,
            mod_w1, mod_b1, mod_b2,
            type_w1, type_b1, type_w2, type_b2,
            pos_w1, pos_b1, pos_w2, pos_b2,
            attn_vec, l, (l != NLVL - 1) ? 1 : 0);
    }

    final_kernel<<<NP / TN, 512, 0, stream>>>(
        buf1, pofeat,
        glob_w1, glob_b1, glob_b2,
        out_b1, out_w2, out_b2,
        (float*)d_out);
}

// Round 15
// 306.426 us; speedup vs baseline: 2.1623x; 1.0235x over previous
//
#include <hip/hip_runtime.h>
#include <math.h>

#define HD   256
#define FIN  32
#define NP   8192
#define PGH  4096
#define NLVL 15
#define TN   16

typedef __attribute__((ext_vector_type(4))) short v4s;
typedef __attribute__((ext_vector_type(8))) short v8s;
typedef __attribute__((ext_vector_type(4))) float v4f;

#define MFMA __builtin_amdgcn_mfma_f32_16x16x32_bf16

// packed bf16 hi/lo fragment-layout weights (written by prep_kernel each launch)
__device__ __align__(16) unsigned short g_wpk[606208];

__device__ __forceinline__ float lrelu(float x) { return x > 0.f ? x : 0.1f * x; }

__device__ __forceinline__ void cvt_duo(float v, unsigned short& hi, unsigned short& lo) {
    unsigned int u = __float_as_uint(v);
    unsigned int r = u + 0x7fffu + ((u >> 16) & 1u);       // RNE to bf16
    hi = (unsigned short)(r >> 16);
    float d = v - __uint_as_float((unsigned int)hi << 16);
    unsigned int u2 = __float_as_uint(d);
    unsigned int r2 = u2 + 0x7fffu + ((u2 >> 16) & 1u);
    lo = (unsigned short)(r2 >> 16);
}

__device__ __forceinline__ v8s pack8(v4s a, v4s b) {
    v8s r; r[0]=a[0]; r[1]=a[1]; r[2]=a[2]; r[3]=a[3]; r[4]=b[0]; r[5]=b[1]; r[6]=b[2]; r[7]=b[3];
    return r;
}

// ---------------- prep: pack weights to bf16 hi/lo MFMA-fragment layout ----------------
__global__ __launch_bounds__(256) void prep_kernel(
    const float* __restrict__ gw1, const float* __restrict__ mw1,
    const float* __restrict__ gw2, const float* __restrict__ mw2,
    const float* __restrict__ glw2, const float* __restrict__ ow1)
{
    int t = blockIdx.x * 256 + threadIdx.x;
    const float* src; int base, N, idx;
    if (t < 36864)       { src = gw1;  base = 0;      N = 128; idx = t; }
    else if (t < 73728)  { src = mw1;  base = 73728;  N = 128; idx = t - 36864; }
    else if (t < 106496) { src = gw2;  base = 147456; N = 256; idx = t - 73728; }
    else if (t < 139264) { src = mw2;  base = 212992; N = 256; idx = t - 106496; }
    else if (t < 172032) { src = glw2; base = 278528; N = 256; idx = t - 139264; }
    else if (t < 303104) { src = ow1;  base = 344064; N = 256; idx = t - 172032; }
    else return;
    int sh = (N == 128) ? 7 : 8;
    int k = idx >> sh, col = idx & (N - 1);
    float v = src[idx];
    unsigned short hi, lo; cvt_duo(v, hi, lo);
    int ks = k >> 5, kk = k & 31;
    int ch = col >> 7, cc = col & 127, ct = cc >> 4;
    int nch = N >> 7;
    int l = ((kk & 15) >> 2) * 16 + (cc & 15);
    int w = (kk & 3) + (kk >> 4) * 4;
    int off = ((ks * nch + ch) * 2) * 4096 + ct * 512 + l * 8 + w;
    g_wpk[base + off] = hi;
    g_wpk[base + off + 4096] = lo;
}

// ---------------- pi kernel: prev_h = mlp(delay), + sdot epilogue (fp32) ----------------
__global__ __launch_bounds__(256) void pi_kernel(
    const float* __restrict__ delay,
    const float* __restrict__ w1, const float* __restrict__ b1,
    const float* __restrict__ w2, const float* __restrict__ b2,
    const float* __restrict__ av,
    float* __restrict__ outh, float* __restrict__ sdot)
{
    __shared__ float g1[TN][132];
    const int tid = threadIdx.x;
    const int node0 = blockIdx.x * TN;

    for (int t = tid; t < TN * 128; t += 256) {
        int i = t >> 7, jj = t & 127;
        g1[i][jj] = lrelu(delay[node0 + i] * w1[jj] + b1[jj]);
    }
    __syncthreads();

    const int j = (tid & 63) * 4;
    const int rg = (tid >> 6) * 4;
    float acc[4][4];
    float4 bv = *(const float4*)&b2[j];
#pragma unroll
    for (int ri = 0; ri < 4; ri++) { acc[ri][0] = bv.x; acc[ri][1] = bv.y; acc[ri][2] = bv.z; acc[ri][3] = bv.w; }

#pragma unroll 2
    for (int k = 0; k < 128; k += 4) {
        float4 x0 = *(const float4*)&g1[rg + 0][k];
        float4 x1 = *(const float4*)&g1[rg + 1][k];
        float4 x2v = *(const float4*)&g1[rg + 2][k];
        float4 x3 = *(const float4*)&g1[rg + 3][k];
        const float* wp = w2 + (size_t)k * 256 + j;
#define PIK(comp, off) { float4 wv = *(const float4*)(wp + (off) * 256); \
    acc[0][0] += x0.comp * wv.x; acc[0][1] += x0.comp * wv.y; acc[0][2] += x0.comp * wv.z; acc[0][3] += x0.comp * wv.w; \
    acc[1][0] += x1.comp * wv.x; acc[1][1] += x1.comp * wv.y; acc[1][2] += x1.comp * wv.z; acc[1][3] += x1.comp * wv.w; \
    acc[2][0] += x2v.comp * wv.x; acc[2][1] += x2v.comp * wv.y; acc[2][2] += x2v.comp * wv.z; acc[2][3] += x2v.comp * wv.w; \
    acc[3][0] += x3.comp * wv.x; acc[3][1] += x3.comp * wv.y; acc[3][2] += x3.comp * wv.z; acc[3][3] += x3.comp * wv.w; }
        PIK(x, 0) PIK(y, 1) PIK(z, 2) PIK(w, 3)
#undef PIK
    }
    float4 avj = *(const float4*)&av[64 + j];
#pragma unroll
    for (int ri = 0; ri < 4; ri++) {
        *(float4*)&outh[(node0 + rg + ri) * HD + j] =
            make_float4(acc[ri][0], acc[ri][1], acc[ri][2], acc[ri][3]);
        float p = acc[ri][0] * avj.x + acc[ri][1] * avj.y + acc[ri][2] * avj.z + acc[ri][3] * avj.w;
#pragma unroll
        for (int off = 1; off < 64; off <<= 1) p += __shfl_xor(p, off);
        if ((tid & 63) == 0) sdot[node0 + rg + ri] = p;
    }
}

// ---------------- per-level kernel: 512 threads; blocks 0..255 gate, 256..511 mod ----------------
__global__ __launch_bounds__(512, 4) void level_kernel(
    const float* __restrict__ prevh, float* __restrict__ nexth,
    const float* __restrict__ sdot_prev, float* __restrict__ sdot_next,
    const float* __restrict__ feat, const float* __restrict__ bitpos,
    const int* __restrict__ srcidx,
    const float* __restrict__ g_w1, const float* __restrict__ g_b1,
    const float* __restrict__ g_b2,
    const float* __restrict__ m_w1, const float* __restrict__ m_b1,
    const float* __restrict__ m_b2,
    const float* __restrict__ t_w1, const float* __restrict__ t_b1,
    const float* __restrict__ t_w2, const float* __restrict__ t_b2,
    const float* __restrict__ p_w1, const float* __restrict__ p_b1,
    const float* __restrict__ p_w2, const float* __restrict__ p_b2,
    const float* __restrict__ av,
    int level, int apply_relu)
{
    __shared__ unsigned short xh_lds[16 * 296];
    __shared__ unsigned short xl_lds[16 * 296];
    __shared__ unsigned short h1h_lds[16 * 136];
    __shared__ unsigned short h1l_lds[16 * 136];
    __shared__ int   src_lds[128];
    __shared__ float dstf_lds[16][32];
    __shared__ float ztt_lds[16][32];
    __shared__ float alpha_lds[128];
    __shared__ float xbp_lds[16];
    __shared__ float av_lds[64];
    __shared__ float tw2av_lds[32];
    __shared__ float pw2av_lds[32];
    __shared__ float bias_av[2];
    __shared__ float red_lds[16][8];

    const int tid = threadIdx.x;
    const bool is_gate = (blockIdx.x < 256);
    const int node0 = is_gate ? (blockIdx.x * TN) : (PGH + ((int)blockIdx.x - 256) * TN);

    const float* w1 = is_gate ? g_w1 : m_w1;
    const float* b1 = is_gate ? g_b1 : m_b1;
    const float* b2 = is_gate ? g_b2 : m_b2;
    const unsigned short* pk1 = g_wpk + (is_gate ? 0 : 73728);
    const unsigned short* pk2 = g_wpk + (is_gate ? 147456 : 212992);

    const int lane = tid & 63, wv = tid >> 6;
    const int lr = lane & 15, lg = lane >> 4;

    // --- early prefetch: GEMM1 B stages 0-1 (land during gather) ---
    const unsigned short* wb1p = pk1 + wv * 512 + lane * 8;
    v8s P1h0 = *(const v8s*)(wb1p);
    v8s P1l0 = *(const v8s*)(wb1p + 4096);
    v8s P1h1 = *(const v8s*)(wb1p + 8192);
    v8s P1l1 = *(const v8s*)(wb1p + 12288);

    // --- early scattered loads for mod logits (sv, bpv) ---
    float sv_r = 0.f, bpv_r = 0.f;
    if (!is_gate && tid < 256) {
        int i = tid >> 4, f = (tid >> 1) & 7;
        int si = srcidx[(level * NP + node0 + i) * 8 + f];
        sv_r = sdot_prev[si];
        bpv_r = bitpos[(level * NP + node0 + i) * 8 + f];
    }

    if (tid < 128) src_lds[tid] = srcidx[(level * NP + node0) * 8 + tid];

    if (is_gate) {
        {
            int i = tid >> 5, k = tid & 31;
            float v = feat[((level + 1) * NP + node0 + i) * FIN + k];
            unsigned short h, l; cvt_duo(v, h, l);
            xh_lds[i * 296 + 256 + k] = h; xl_lds[i * 296 + 256 + k] = l;
        }
        // no barrier needed: gather writes disjoint LDS columns; first reader is post-gather
        __syncthreads();   // src_lds visible
        {
            const int c = tid & 255, sh = (tid >> 8) * 8;
            for (int s0 = 0; s0 < 8; s0 += 4) {
                const int* spA = &src_lds[(sh + s0 + 0) * 8];
                const int* spB = &src_lds[(sh + s0 + 1) * 8];
                const int* spC = &src_lds[(sh + s0 + 2) * 8];
                const int* spD = &src_lds[(sh + s0 + 3) * 8];
                float ma[8], mb[8], mc[8], md[8];
#pragma unroll
                for (int f = 0; f < 8; f++) ma[f] = prevh[spA[f] * HD + c];
#pragma unroll
                for (int f = 0; f < 8; f++) mb[f] = prevh[spB[f] * HD + c];
#pragma unroll
                for (int f = 0; f < 8; f++) mc[f] = prevh[spC[f] * HD + c];
#pragma unroll
                for (int f = 0; f < 8; f++) md[f] = prevh[spD[f] * HD + c];
                float mxa = -1e30f, mxb = -1e30f, mxc = -1e30f, mxd = -1e30f;
#pragma unroll
                for (int f = 0; f < 8; f++) {
                    mxa = fmaxf(mxa, ma[f]); mxb = fmaxf(mxb, mb[f]);
                    mxc = fmaxf(mxc, mc[f]); mxd = fmaxf(mxd, md[f]);
                }
                float sa = 0.f, wsa = 0.f, sb = 0.f, wsb = 0.f;
                float sc = 0.f, wsc = 0.f, sd = 0.f, wsd = 0.f;
#pragma unroll
                for (int f = 0; f < 8; f++) {
                    float ea = __expf(ma[f] - mxa); sa += ea; wsa += ma[f] * ea;
                    float eb = __expf(mb[f] - mxb); sb += eb; wsb += mb[f] * eb;
                    float ec = __expf(mc[f] - mxc); sc += ec; wsc += mc[f] * ec;
                    float ed = __expf(md[f] - mxd); sd += ed; wsd += md[f] * ed;
                }
                unsigned short h, l;
                cvt_duo(wsa / sa, h, l); xh_lds[(sh+s0+0)*296 + c] = h; xl_lds[(sh+s0+0)*296 + c] = l;
                cvt_duo(wsb / sb, h, l); xh_lds[(sh+s0+1)*296 + c] = h; xl_lds[(sh+s0+1)*296 + c] = l;
                cvt_duo(wsc / sc, h, l); xh_lds[(sh+s0+2)*296 + c] = h; xl_lds[(sh+s0+2)*296 + c] = l;
                cvt_duo(wsd / sd, h, l); xh_lds[(sh+s0+3)*296 + c] = h; xl_lds[(sh+s0+3)*296 + c] = l;
            }
        }
        __syncthreads();
    } else {
        {
            int i = tid >> 5, k = tid & 31;
            float v = feat[((level + 1) * NP + node0 + i) * FIN + k];
            dstf_lds[i][k] = v;
            unsigned short h, l; cvt_duo(v, h, l);
            xh_lds[i * 296 + 257 + k] = h; xl_lds[i * 296 + 257 + k] = l;
        }
        if (tid < 64) av_lds[tid] = av[tid];
        __syncthreads();

        // ztt = lrelu(dstf @ t_w1 + t_b1)
        {
            int i = tid >> 5, jj = tid & 31;
            float a = t_b1[jj];
#pragma unroll 8
            for (int k = 0; k < 32; k++) a += dstf_lds[i][k] * t_w1[k * 32 + jj];
            ztt_lds[i][jj] = lrelu(a);
        }
        if (tid < 32) {
            float s = 0.f;
#pragma unroll 8
            for (int jj = 0; jj < 32; jj++) s += t_w2[tid * 32 + jj] * av_lds[jj];
            tw2av_lds[tid] = s;
        } else if (tid < 64) {
            int k = tid - 32;
            float s = 0.f;
#pragma unroll 8
            for (int jj = 0; jj < 32; jj++) s += p_w2[k * 32 + jj] * av_lds[32 + jj];
            pw2av_lds[k] = s;
        } else if (tid == 64) {
            float s = 0.f;
#pragma unroll 8
            for (int jj = 0; jj < 32; jj++) s += t_b2[jj] * av_lds[jj];
            bias_av[0] = s;
        } else if (tid == 65) {
            float s = 0.f;
#pragma unroll 8
            for (int jj = 0; jj < 32; jj++) s += p_b2[jj] * av_lds[32 + jj];
            bias_av[1] = s;
        }
        __syncthreads();

        // logits + softmax over fanin (sv/bpv pre-loaded at kernel entry)
        if (tid < 256) {
            const int jg = tid & 1, f = (tid >> 1) & 7, i = tid >> 4;
            const float bpv = bpv_r;
            float part = 0.f;
            const int k0 = jg * 16;
#pragma unroll
            for (int k = k0; k < k0 + 16; k++) {
                float h1pk = lrelu(bpv * p_w1[k] + p_b1[k]);
                part += h1pk * pw2av_lds[k];
                part += ztt_lds[i][k] * tw2av_lds[k];
            }
            part += __shfl_xor(part, 1);
            float logit = part + bias_av[0] + bias_av[1] + sv_r;
            float mx = logit;
            mx = fmaxf(mx, __shfl_xor(mx, 2));
            mx = fmaxf(mx, __shfl_xor(mx, 4));
            mx = fmaxf(mx, __shfl_xor(mx, 8));
            float e = __expf(logit - mx);
            float ssum = e;
            ssum += __shfl_xor(ssum, 2);
            ssum += __shfl_xor(ssum, 4);
            ssum += __shfl_xor(ssum, 8);
            float alpha = e / ssum;
            if (jg == 0) alpha_lds[i * 8 + f] = alpha;
            float ab = alpha * bpv;
            ab += __shfl_xor(ab, 2);
            ab += __shfl_xor(ab, 4);
            ab += __shfl_xor(ab, 8);
            if ((tid & 15) == 0) xbp_lds[i] = ab;
        }
        __syncthreads();

        // neigh_m: thread = (half, channel), 4-node chunks; write x duo
        {
            const int c = tid & 255, sh = (tid >> 8) * 8;
            for (int s0 = 0; s0 < 8; s0 += 4) {
                const int* spA = &src_lds[(sh + s0 + 0) * 8];
                const int* spB = &src_lds[(sh + s0 + 1) * 8];
                const int* spC = &src_lds[(sh + s0 + 2) * 8];
                const int* spD = &src_lds[(sh + s0 + 3) * 8];
                float ma[8], mb[8], mc[8], md[8];
#pragma unroll
                for (int f = 0; f < 8; f++) ma[f] = prevh[spA[f] * HD + c];
#pragma unroll
                for (int f = 0; f < 8; f++) mb[f] = prevh[spB[f] * HD + c];
#pragma unroll
                for (int f = 0; f < 8; f++) mc[f] = prevh[spC[f] * HD + c];
#pragma unroll
                for (int f = 0; f < 8; f++) md[f] = prevh[spD[f] * HD + c];
                const float* apA = &alpha_lds[(sh + s0 + 0) * 8];
                const float* apB = &alpha_lds[(sh + s0 + 1) * 8];
                const float* apC = &alpha_lds[(sh + s0 + 2) * 8];
                const float* apD = &alpha_lds[(sh + s0 + 3) * 8];
                float aa = 0.f, ab2 = 0.f, ac = 0.f, ad = 0.f;
#pragma unroll
                for (int f = 0; f < 8; f++) {
                    aa  += apA[f] * ma[f]; ab2 += apB[f] * mb[f];
                    ac  += apC[f] * mc[f]; ad  += apD[f] * md[f];
                }
                unsigned short h, l;
                cvt_duo(aa,  h, l); xh_lds[(sh+s0+0)*296 + c] = h; xl_lds[(sh+s0+0)*296 + c] = l;
                cvt_duo(ab2, h, l); xh_lds[(sh+s0+1)*296 + c] = h; xl_lds[(sh+s0+1)*296 + c] = l;
                cvt_duo(ac,  h, l); xh_lds[(sh+s0+2)*296 + c] = h; xl_lds[(sh+s0+2)*296 + c] = l;
                cvt_duo(ad,  h, l); xh_lds[(sh+s0+3)*296 + c] = h; xl_lds[(sh+s0+3)*296 + c] = l;
            }
        }
        if (tid < TN) {
            unsigned short h, l; cvt_duo(xbp_lds[tid], h, l);
            xh_lds[tid * 296 + 256] = h; xl_lds[tid * 296 + 256] = l;
        }
        __syncthreads();
    }

    // ---------- GEMM1 (MFMA bf16x3): (16 x 288) @ (288 x 128); stages 0-1 prefetched ----------
    {
        const unsigned short* xrh = xh_lds + lr * 296 + 4 * lg;
        const unsigned short* xrl = xl_lds + lr * 296 + 4 * lg;
        const int colg = wv * 16 + lr;
        float bb = b1[colg];
        v4f acc = {bb, bb, bb, bb};
        {
            v8s Ah = pack8(*(const v4s*)(xrh), *(const v4s*)(xrh + 16));
            v8s Al = pack8(*(const v4s*)(xrl), *(const v4s*)(xrl + 16));
            acc = MFMA(Ah, P1h0, acc, 0, 0, 0);
            acc = MFMA(Ah, P1l0, acc, 0, 0, 0);
            acc = MFMA(Al, P1h0, acc, 0, 0, 0);
            v8s Ah1 = pack8(*(const v4s*)(xrh + 32), *(const v4s*)(xrh + 48));
            v8s Al1 = pack8(*(const v4s*)(xrl + 32), *(const v4s*)(xrl + 48));
            acc = MFMA(Ah1, P1h1, acc, 0, 0, 0);
            acc = MFMA(Ah1, P1l1, acc, 0, 0, 0);
            acc = MFMA(Al1, P1h1, acc, 0, 0, 0);
        }
#pragma unroll
        for (int s = 2; s < 9; ++s) {
            const unsigned short* wb = pk1 + s * 8192 + wv * 512 + lane * 8;
            v8s Bh = *(const v8s*)(wb);
            v8s Bl = *(const v8s*)(wb + 4096);
            int k0 = s * 32;
            v8s Ah = pack8(*(const v4s*)(xrh + k0), *(const v4s*)(xrh + k0 + 16));
            v8s Al = pack8(*(const v4s*)(xrl + k0), *(const v4s*)(xrl + k0 + 16));
            acc = MFMA(Ah, Bh, acc, 0, 0, 0);
            acc = MFMA(Ah, Bl, acc, 0, 0, 0);
            acc = MFMA(Al, Bh, acc, 0, 0, 0);
        }
        // prefetch GEMM2 stage (ks=0, both col chunks); lands during epilogue + barrier
        const unsigned short* wb2p = pk2 + wv * 512 + lane * 8;
        v8s P2h0 = *(const v8s*)(wb2p);
        v8s P2l0 = *(const v8s*)(wb2p + 4096);
        v8s P2h1 = *(const v8s*)(wb2p + 8192);
        v8s P2l1 = *(const v8s*)(wb2p + 12288);

        float w288 = is_gate ? 0.f : w1[288 * 128 + colg];
#pragma unroll
        for (int r = 0; r < 4; ++r) {
            int row = lg * 4 + r;
            float v = acc[r];
            if (!is_gate) v += dstf_lds[row][31] * w288;
            v = lrelu(v);
            unsigned short h, l; cvt_duo(v, h, l);
            h1h_lds[row * 136 + colg] = h;
            h1l_lds[row * 136 + colg] = l;
        }
        __syncthreads();

        // ---------- GEMM2 (MFMA bf16x3): (16 x 128) @ (128 x 256) + relu + sdot ----------
        const unsigned short* h1rh = h1h_lds + lr * 136 + 4 * lg;
        const unsigned short* h1rl = h1l_lds + lr * 136 + 4 * lg;
        const int col0 = wv * 16 + lr;
        float bb0 = b2[col0], bb1 = b2[128 + col0];
        v4f acc0 = {bb0, bb0, bb0, bb0};
        v4f acc1 = {bb1, bb1, bb1, bb1};
        {
            v8s Ah = pack8(*(const v4s*)(h1rh), *(const v4s*)(h1rh + 16));
            v8s Al = pack8(*(const v4s*)(h1rl), *(const v4s*)(h1rl + 16));
            acc0 = MFMA(Ah, P2h0, acc0, 0, 0, 0);
            acc0 = MFMA(Ah, P2l0, acc0, 0, 0, 0);
            acc0 = MFMA(Al, P2h0, acc0, 0, 0, 0);
            acc1 = MFMA(Ah, P2h1, acc1, 0, 0, 0);
            acc1 = MFMA(Ah, P2l1, acc1, 0, 0, 0);
            acc1 = MFMA(Al, P2h1, acc1, 0, 0, 0);
        }
#pragma unroll
        for (int ks = 1; ks < 4; ++ks) {
            int k0 = ks * 32;
            v8s Ah = pack8(*(const v4s*)(h1rh + k0), *(const v4s*)(h1rh + k0 + 16));
            v8s Al = pack8(*(const v4s*)(h1rl + k0), *(const v4s*)(h1rl + k0 + 16));
            const unsigned short* wb0 = pk2 + (ks * 2 + 0) * 8192 + wv * 512 + lane * 8;
            const unsigned short* wb1 = pk2 + (ks * 2 + 1) * 8192 + wv * 512 + lane * 8;
            v8s Bh0 = *(const v8s*)(wb0);
            v8s Bl0 = *(const v8s*)(wb0 + 4096);
            v8s Bh1 = *(const v8s*)(wb1);
            v8s Bl1 = *(const v8s*)(wb1 + 4096);
            acc0 = MFMA(Ah, Bh0, acc0, 0, 0, 0);
            acc0 = MFMA(Ah, Bl0, acc0, 0, 0, 0);
            acc0 = MFMA(Al, Bh0, acc0, 0, 0, 0);
            acc1 = MFMA(Ah, Bh1, acc1, 0, 0, 0);
            acc1 = MFMA(Ah, Bl1, acc1, 0, 0, 0);
            acc1 = MFMA(Al, Bh1, acc1, 0, 0, 0);
        }
        float pr[4] = {0.f, 0.f, 0.f, 0.f};
#pragma unroll
        for (int r = 0; r < 4; ++r) {
            int row = lg * 4 + r;
            float v = acc0[r];
            if (apply_relu) v = fmaxf(v, 0.f);
            nexth[(node0 + row) * HD + col0] = v;
            pr[r] += v * av[64 + col0];
            float v2 = acc1[r];
            if (apply_relu) v2 = fmaxf(v2, 0.f);
            nexth[(node0 + row) * HD + 128 + col0] = v2;
            pr[r] += v2 * av[192 + col0];
        }
#pragma unroll
        for (int off = 1; off < 16; off <<= 1) {
#pragma unroll
            for (int r = 0; r < 4; ++r) pr[r] += __shfl_xor(pr[r], off);
        }
        if (lr == 0) {
#pragma unroll
            for (int r = 0; r < 4; ++r) red_lds[lg * 4 + r][wv] = pr[r];
        }
        __syncthreads();
        if (tid < TN) {
            float s = 0.f;
#pragma unroll
            for (int w = 0; w < 8; w++) s += red_lds[tid][w];
            sdot_next[node0 + tid] = s;
        }
    }
}

// ---------------- final kernel: 512 threads; glob mlp + concat + out mlp (fused, MFMA) ----------------
__global__ __launch_bounds__(512, 4) void final_kernel(
    const float* __restrict__ prevh, const float* __restrict__ pofeat,
    const float* __restrict__ gl_w1, const float* __restrict__ gl_b1,
    const float* __restrict__ gl_b2,
    const float* __restrict__ o_b1,
    const float* __restrict__ o_w2, const float* __restrict__ o_b2,
    float* __restrict__ out)
{
    __shared__ unsigned short x2h[16 * 520];
    __shared__ unsigned short x2l[16 * 520];
    __shared__ unsigned short g1h[16 * 136];
    __shared__ unsigned short g1l[16 * 136];
    __shared__ float ow2_lds[256];
    __shared__ float red_lds[16][8];

    const int tid = threadIdx.x;
    const int node0 = blockIdx.x * TN;
    const unsigned short* pkG = g_wpk + 278528;
    const unsigned short* pkO = g_wpk + 344064;

    const int lane = tid & 63, wv = tid >> 6;
    const int lr = lane & 15, lg = lane >> 4;
    const int col0 = wv * 16 + lr;

    // early prefetch: glob stage ks=0, both col chunks
    const unsigned short* wbgp = pkG + wv * 512 + lane * 8;
    v8s PGh0 = *(const v8s*)(wbgp);
    v8s PGl0 = *(const v8s*)(wbgp + 4096);
    v8s PGh1 = *(const v8s*)(wbgp + 8192);
    v8s PGl1 = *(const v8s*)(wbgp + 12288);

    for (int q = tid; q < TN * 64; q += 512) {
        int i = q >> 6, c4 = (q & 63) * 4;
        float4 v = *(const float4*)&prevh[(node0 + i) * HD + c4];
        unsigned short h, l;
        cvt_duo(v.x, h, l); x2h[i * 520 + c4 + 0] = h; x2l[i * 520 + c4 + 0] = l;
        cvt_duo(v.y, h, l); x2h[i * 520 + c4 + 1] = h; x2l[i * 520 + c4 + 1] = l;
        cvt_duo(v.z, h, l); x2h[i * 520 + c4 + 2] = h; x2l[i * 520 + c4 + 2] = l;
        cvt_duo(v.w, h, l); x2h[i * 520 + c4 + 3] = h; x2l[i * 520 + c4 + 3] = l;
    }
    for (int t = tid; t < TN * 128; t += 512) {
        int i = t >> 7, jj = t & 127;
        float v = lrelu(pofeat[node0 + i] * gl_w1[jj] + gl_b1[jj]);
        unsigned short h, l; cvt_duo(v, h, l);
        g1h[i * 136 + jj] = h; g1l[i * 136 + jj] = l;
    }
    if (tid < 256) ow2_lds[tid] = o_w2[tid];
    __syncthreads();

    // glob layer 2 (MFMA): (16x128)@(128x256) -> x2 duo cols 256..511
    {
        const unsigned short* grh = g1h + lr * 136 + 4 * lg;
        const unsigned short* grl = g1l + lr * 136 + 4 * lg;
        float bb0 = gl_b2[col0], bb1 = gl_b2[128 + col0];
        v4f acc0 = {bb0, bb0, bb0, bb0};
        v4f acc1 = {bb1, bb1, bb1, bb1};
        {
            v8s Ah = pack8(*(const v4s*)(grh), *(const v4s*)(grh + 16));
            v8s Al = pack8(*(const v4s*)(grl), *(const v4s*)(grl + 16));
            acc0 = MFMA(Ah, PGh0, acc0, 0, 0, 0);
            acc0 = MFMA(Ah, PGl0, acc0, 0, 0, 0);
            acc0 = MFMA(Al, PGh0, acc0, 0, 0, 0);
            acc1 = MFMA(Ah, PGh1, acc1, 0, 0, 0);
            acc1 = MFMA(Ah, PGl1, acc1, 0, 0, 0);
            acc1 = MFMA(Al, PGh1, acc1, 0, 0, 0);
        }
#pragma unroll
        for (int ks = 1; ks < 4; ++ks) {
            int k0 = ks * 32;
            v8s Ah = pack8(*(const v4s*)(grh + k0), *(const v4s*)(grh + k0 + 16));
            v8s Al = pack8(*(const v4s*)(grl + k0), *(const v4s*)(grl + k0 + 16));
            const unsigned short* wb0 = pkG + (ks * 2 + 0) * 8192 + wv * 512 + lane * 8;
            const unsigned short* wb1 = pkG + (ks * 2 + 1) * 8192 + wv * 512 + lane * 8;
            v8s Bh0 = *(const v8s*)(wb0);
            v8s Bl0 = *(const v8s*)(wb0 + 4096);
            v8s Bh1 = *(const v8s*)(wb1);
            v8s Bl1 = *(const v8s*)(wb1 + 4096);
            acc0 = MFMA(Ah, Bh0, acc0, 0, 0, 0);
            acc0 = MFMA(Ah, Bl0, acc0, 0, 0, 0);
            acc0 = MFMA(Al, Bh0, acc0, 0, 0, 0);
            acc1 = MFMA(Ah, Bh1, acc1, 0, 0, 0);
            acc1 = MFMA(Ah, Bl1, acc1, 0, 0, 0);
            acc1 = MFMA(Al, Bh1, acc1, 0, 0, 0);
        }
        // prefetch out1 stage ks=0 (lands during epilogue + barrier)
        const unsigned short* wbop = pkO + wv * 512 + lane * 8;
        v8s POh0 = *(const v8s*)(wbop);
        v8s POl0 = *(const v8s*)(wbop + 4096);
        v8s POh1 = *(const v8s*)(wbop + 8192);
        v8s POl1 = *(const v8s*)(wbop + 12288);

#pragma unroll
        for (int r = 0; r < 4; ++r) {
            int row = lg * 4 + r;
            unsigned short h, l;
            cvt_duo(acc0[r], h, l); x2h[row * 520 + 256 + col0] = h; x2l[row * 520 + 256 + col0] = l;
            cvt_duo(acc1[r], h, l); x2h[row * 520 + 384 + col0] = h; x2l[row * 520 + 384 + col0] = l;
        }
        __syncthreads();

        // out layer 1 (MFMA, K=512, 16 K-stages x 2 col-chunks) fused with out layer 2
        const unsigned short* xrh = x2h + lr * 520 + 4 * lg;
        const unsigned short* xrl = x2l + lr * 520 + 4 * lg;
        float ob0 = o_b1[col0], ob1 = o_b1[128 + col0];
        v4f oacc0 = {ob0, ob0, ob0, ob0};
        v4f oacc1 = {ob1, ob1, ob1, ob1};
        {
            v8s Ah = pack8(*(const v4s*)(xrh), *(const v4s*)(xrh + 16));
            v8s Al = pack8(*(const v4s*)(xrl), *(const v4s*)(xrl + 16));
            oacc0 = MFMA(Ah, POh0, oacc0, 0, 0, 0);
            oacc0 = MFMA(Ah, POl0, oacc0, 0, 0, 0);
            oacc0 = MFMA(Al, POh0, oacc0, 0, 0, 0);
            oacc1 = MFMA(Ah, POh1, oacc1, 0, 0, 0);
            oacc1 = MFMA(Ah, POl1, oacc1, 0, 0, 0);
            oacc1 = MFMA(Al, POh1, oacc1, 0, 0, 0);
        }
        for (int ks = 1; ks < 16; ++ks) {
            int k0 = ks * 32;
            v8s Ah = pack8(*(const v4s*)(xrh + k0), *(const v4s*)(xrh + k0 + 16));
            v8s Al = pack8(*(const v4s*)(xrl + k0), *(const v4s*)(xrl + k0 + 16));
            const unsigned short* wb0 = pkO + (ks * 2 + 0) * 8192 + wv * 512 + lane * 8;
            const unsigned short* wb1 = pkO + (ks * 2 + 1) * 8192 + wv * 512 + lane * 8;
            v8s Bh0 = *(const v8s*)(wb0);
            v8s Bl0 = *(const v8s*)(wb0 + 4096);
            v8s Bh1 = *(const v8s*)(wb1);
            v8s Bl1 = *(const v8s*)(wb1 + 4096);
            oacc0 = MFMA(Ah, Bh0, oacc0, 0, 0, 0);
            oacc0 = MFMA(Ah, Bl0, oacc0, 0, 0, 0);
            oacc0 = MFMA(Al, Bh0, oacc0, 0, 0, 0);
            oacc1 = MFMA(Ah, Bh1, oacc1, 0, 0, 0);
            oacc1 = MFMA(Ah, Bl1, oacc1, 0, 0, 0);
            oacc1 = MFMA(Al, Bh1, oacc1, 0, 0, 0);
        }
        float pr[4] = {0.f, 0.f, 0.f, 0.f};
#pragma unroll
        for (int r = 0; r < 4; ++r) {
            pr[r] += lrelu(oacc0[r]) * ow2_lds[col0];
            pr[r] += lrelu(oacc1[r]) * ow2_lds[128 + col0];
        }
#pragma unroll
        for (int off = 1; off < 16; off <<= 1) {
#pragma unroll
            for (int r = 0; r < 4; ++r) pr[r] += __shfl_xor(pr[r], off);
        }
        if (lr == 0) {
#pragma unroll
            for (int r = 0; r < 4; ++r) red_lds[lg * 4 + r][wv] = pr[r];
        }
        __syncthreads();
        if (tid < TN) {
            float s = 0.f;
#pragma unroll
            for (int w = 0; w < 8; w++) s += red_lds[tid][w];
            out[node0 + tid] = s + o_b2[0];
        }
    }
}

extern "C" void kernel_launch(void* const* d_in, const int* in_sizes, int n_in,
                              void* d_out, int out_size, void* d_ws, size_t ws_size,
                              hipStream_t stream)
{
    const float* delay    = (const float*)d_in[0];
    const float* feat     = (const float*)d_in[1];
    const float* bitpos   = (const float*)d_in[2];
    const float* pofeat   = (const float*)d_in[3];
    const int*   srcidx   = (const int*)  d_in[4];
    const float* pi_w1    = (const float*)d_in[5];
    const float* pi_b1    = (const float*)d_in[6];
    const float* pi_w2    = (const float*)d_in[7];
    const float* pi_b2    = (const float*)d_in[8];
    const float* gate_w1  = (const float*)d_in[9];
    const float* gate_b1  = (const float*)d_in[10];
    const float* gate_w2  = (const float*)d_in[11];
    const float* gate_b2  = (const float*)d_in[12];
    const float* mod_w1   = (const float*)d_in[13];
    const float* mod_b1   = (const float*)d_in[14];
    const float* mod_w2   = (const float*)d_in[15];
    const float* mod_b2   = (const float*)d_in[16];
    const float* type_w1  = (const float*)d_in[17];
    const float* type_b1  = (const float*)d_in[18];
    const float* type_w2  = (const float*)d_in[19];
    const float* type_b2  = (const float*)d_in[20];
    const float* pos_w1   = (const float*)d_in[21];
    const float* pos_b1   = (const float*)d_in[22];
    const float* pos_w2   = (const float*)d_in[23];
    const float* pos_b2   = (const float*)d_in[24];
    const float* attn_vec = (const float*)d_in[25];
    const float* glob_w1  = (const float*)d_in[26];
    const float* glob_b1  = (const float*)d_in[27];
    const float* glob_w2  = (const float*)d_in[28];
    const float* glob_b2  = (const float*)d_in[29];
    const float* out_w1   = (const float*)d_in[30];
    const float* out_b1   = (const float*)d_in[31];
    const float* out_w2   = (const float*)d_in[32];
    const float* out_b2   = (const float*)d_in[33];

    float* buf0 = (float*)d_ws;
    float* buf1 = buf0 + (size_t)NP * HD;
    float* sd0  = buf1 + (size_t)NP * HD;
    float* sd1  = sd0 + NP;

    prep_kernel<<<1184, 256, 0, stream>>>(gate_w1, mod_w1, gate_w2, mod_w2, glob_w2, out_w1);

    pi_kernel<<<NP / TN, 256, 0, stream>>>(delay, pi_w1, pi_b1, pi_w2, pi_b2,
                                           attn_vec, buf0, sd0);

    for (int l = 0; l < NLVL; l++) {
        float* pv = (l & 1) ? buf1 : buf0;
        float* nx = (l & 1) ? buf0 : buf1;
        float* sp = (l & 1) ? sd1 : sd0;
        float* sn = (l & 1) ? sd0 : sd1;
        level_kernel<<<NP / TN, 512, 0, stream>>>(
            pv, nx, sp, sn, feat, bitpos, srcidx,
            gate_w1, gate_b1, gate_b2,
            mod_w1, mod_b1, mod_b2,
            type_w1, type_b1, type_w2, type_b2,
            pos_w1, pos_b1, pos_w2, pos_b2,
            attn_vec, l, (l != NLVL - 1) ? 1 : 0);
    }

    final_kernel<<<NP / TN, 512, 0, stream>>>(
        buf1, pofeat,
        glob_w1, glob_b1, glob_b2,
        out_b1, out_w2, out_b2,
        (float*)d_out);
}